// Round 13
// baseline (506.962 us; speedup 1.0000x reference)
//
#include <hip/hip_runtime.h>
#include <hip/hip_bf16.h>
#include <stdint.h>

#define DI __device__ __forceinline__

typedef short bf16x8_t __attribute__((ext_vector_type(8)));
typedef float f32x4_t __attribute__((ext_vector_type(4)));

DI unsigned short f2bf(float f) {
  __hip_bfloat16 h = __float2bfloat16(f);
  unsigned short u;
  __builtin_memcpy(&u, &h, 2);
  return u;
}

// pair f32 -> packed 2xbf16 (compiler emits v_cvt_pk_bf16_f32)
DI uint32_t pk2(float a, float b) {
  return (uint32_t)f2bf(a) | ((uint32_t)f2bf(b) << 16);
}

DI f32x4_t mfma16(bf16x8_t a, bf16x8_t b, f32x4_t c) {
  return __builtin_amdgcn_mfma_f32_16x16x32_bf16(a, b, c, 0, 0, 0);
}

DI void gload16(const void* g, void* l) {
  __builtin_amdgcn_global_load_lds(
      (const __attribute__((address_space(1))) uint32_t*)g,
      (__attribute__((address_space(3))) uint32_t*)l, 16, 0, 0);
}

// A/B tile fragment read with chunk swizzle matching pre-swizzled global source:
// lds[row][chunk ^ ((row>>1)&3)], tile row = 32 shorts (64B), chunk = 8 shorts (16B)
DI bf16x8_t frag(const unsigned short* base, int row, int hi) {
  return *(const bf16x8_t*)&base[row * 32 + ((hi ^ ((row >> 1) & 3)) * 8)];
}
// per-lane source chunk offset (in shorts) for gload16 A/B staging
DI int chunk_swz(int tid) { return ((tid & 3) ^ ((tid >> 3) & 3)) * 8; }

// ---------------- fused transpose + f32->bf16 for 4 square matrices (z selects) ----------
__global__ __launch_bounds__(256) void transpose_cvt4(const float* __restrict__ s0, const float* __restrict__ s1,
                                                      const float* __restrict__ s2, const float* __restrict__ s3,
                                                      unsigned short* __restrict__ d0, unsigned short* __restrict__ d1,
                                                      unsigned short* __restrict__ d2, unsigned short* __restrict__ d3) {
  __shared__ float tile[64][65];
  const int z = blockIdx.z;
  const float* in = (z == 0) ? s0 : (z == 1) ? s1 : (z == 2) ? s2 : s3;
  unsigned short* out = (z == 0) ? d0 : (z == 1) ? d1 : (z == 2) ? d2 : d3;
  const int tid = threadIdx.x;
  const int tx = tid & 15, ty = tid >> 4;
  const int r0 = blockIdx.y * 64, c0 = blockIdx.x * 64;
#pragma unroll
  for (int i = 0; i < 4; ++i) {
    const int r = ty + i * 16;
    const float4 v = *(const float4*)(in + (size_t)(r0 + r) * 1024 + c0 + tx * 4);
    tile[r][tx * 4 + 0] = v.x; tile[r][tx * 4 + 1] = v.y;
    tile[r][tx * 4 + 2] = v.z; tile[r][tx * 4 + 3] = v.w;
  }
  __syncthreads();
#pragma unroll
  for (int i = 0; i < 4; ++i) {
    const int r = ty + i * 16;
    ushort4 o;
    o.x = f2bf(tile[tx * 4 + 0][r]); o.y = f2bf(tile[tx * 4 + 1][r]);
    o.z = f2bf(tile[tx * 4 + 2][r]); o.w = f2bf(tile[tx * 4 + 3][r]);
    *(ushort4*)(out + (size_t)(c0 + r) * 1024 + r0 + tx * 4) = o;
  }
}

// ---------------- LayerNorm f32 -> bf16 ----------------
__global__ __launch_bounds__(256) void ln_kernel(const float* __restrict__ x, const float* __restrict__ g,
                                                 const float* __restrict__ b, unsigned short* __restrict__ out) {
  const int row = blockIdx.x, tid = threadIdx.x;
  const int wid = tid >> 6, lane = tid & 63;
  const float4 v = *(const float4*)(x + (size_t)row * 1024 + tid * 4);
  float s = v.x + v.y + v.z + v.w;
  float s2 = v.x * v.x + v.y * v.y + v.z * v.z + v.w * v.w;
#pragma unroll
  for (int o = 1; o < 64; o <<= 1) { s += __shfl_xor(s, o); s2 += __shfl_xor(s2, o); }
  __shared__ float red[8];
  if (lane == 0) { red[wid] = s; red[4 + wid] = s2; }
  __syncthreads();
  const float ts = red[0] + red[1] + red[2] + red[3];
  const float ts2 = red[4] + red[5] + red[6] + red[7];
  const float mu = ts * 0.0009765625f;
  const float var = ts2 * 0.0009765625f - mu * mu;
  const float rs = rsqrtf(var + 1e-5f);
  const float4 gg = *(const float4*)(g + tid * 4);
  const float4 bb = *(const float4*)(b + tid * 4);
  ushort4 o4;
  o4.x = f2bf((v.x - mu) * rs * gg.x + bb.x);
  o4.y = f2bf((v.y - mu) * rs * gg.y + bb.y);
  o4.z = f2bf((v.z - mu) * rs * gg.z + bb.z);
  o4.w = f2bf((v.w - mu) * rs * gg.w + bb.w);
  *(ushort4*)(out + (size_t)row * 1024 + tid * 4) = o4;
}

// ---------------- generic bf16 GEMM core: BM=128, BK=32, 256 thr, waves 2x2 ----------------
template<int BN>
DI void gemm_loop(const unsigned short* aR0, const unsigned short* aR1,
                  const unsigned short* bR0, const unsigned short* bR1,
                  const int K, unsigned short* lds, const int tid,
                  f32x4_t (&acc)[4][BN / 32]) {
  constexpr int NF = BN / 32;
  unsigned short* ldsA = lds;
  unsigned short* ldsB = lds + 4096;  // 128*32
  const int wid = tid >> 6, lane = tid & 63, ln = lane & 15, hi = lane >> 4;
  const int wr = wid >> 1, wc = wid & 1;
  char* dstA0 = (char*)ldsA + wid * 1024;
  char* dstA1 = (char*)ldsA + 4096 + wid * 1024;
  char* dstB0 = (char*)ldsB + wid * 1024;
  char* dstB1 = (char*)ldsB + 4096 + wid * 1024;
  for (int k0 = 0; k0 < K; k0 += 32) {
    gload16(aR0 + k0, dstA0);
    gload16(aR1 + k0, dstA1);
    gload16(bR0 + k0, dstB0);
    if constexpr (BN == 128) gload16(bR1 + k0, dstB1);
    __syncthreads();
    bf16x8_t af[4];
#pragma unroll
    for (int mf = 0; mf < 4; ++mf)
      af[mf] = frag(ldsA, wr * 64 + mf * 16 + ln, hi);
    __builtin_amdgcn_s_setprio(1);
#pragma unroll
    for (int nf = 0; nf < NF; ++nf) {
      bf16x8_t bfr = frag(ldsB, wc * (BN / 2) + nf * 16 + ln, hi);
#pragma unroll
      for (int mf = 0; mf < 4; ++mf)
        acc[mf][nf] = mfma16(af[mf], bfr, acc[mf][nf]);
    }
    __builtin_amdgcn_s_setprio(0);
    __syncthreads();
  }
}

// ---------------- QKV projections (z = 0:Q, 1:K, 2:V-transposed) ----------------
__global__ __launch_bounds__(256) void qkv_kernel(const unsigned short* __restrict__ h1,
                                                  const unsigned short* __restrict__ wqT,
                                                  const unsigned short* __restrict__ wkT,
                                                  const unsigned short* __restrict__ wvT,
                                                  unsigned short* __restrict__ qb,
                                                  unsigned short* __restrict__ kbf,
                                                  unsigned short* __restrict__ vt) {
  __shared__ unsigned short lds[128 * 32 + 128 * 32];
  const int tid = threadIdx.x;
  const int z = blockIdx.z;
  const unsigned short* BT = (z == 0) ? wqT : (z == 1) ? wkT : wvT;
  const int m0 = blockIdx.y * 128, n0 = blockIdx.x * 128;
  f32x4_t acc[4][4] = {};
  const int cs = chunk_swz(tid);
  const unsigned short* aR0 = h1 + (size_t)(m0 + (tid >> 2)) * 1024 + cs;
  const unsigned short* aR1 = aR0 + 64 * 1024;
  const unsigned short* bR0 = BT + (size_t)(n0 + (tid >> 2)) * 1024 + cs;
  const unsigned short* bR1 = bR0 + 64 * 1024;
  gemm_loop<128>(aR0, aR1, bR0, bR1, 1024, lds, tid, acc);
  const int lane = tid & 63, ln = lane & 15, hi = lane >> 4, wid = tid >> 6;
  const int wr = wid >> 1, wc = wid & 1;
  if (z < 2) {
    unsigned short* o = z ? kbf : qb;
#pragma unroll
    for (int mf = 0; mf < 4; ++mf)
#pragma unroll
      for (int nf = 0; nf < 4; ++nf)
#pragma unroll
        for (int r = 0; r < 4; ++r) {
          const int m = m0 + wr * 64 + mf * 16 + hi * 4 + r;
          const int n = n0 + wc * 64 + nf * 16 + ln;
          o[(size_t)m * 1024 + n] = f2bf(acc[mf][nf][r]);
        }
  } else {
#pragma unroll
    for (int mf = 0; mf < 4; ++mf)
#pragma unroll
      for (int nf = 0; nf < 4; ++nf) {
        const int n = n0 + wc * 64 + nf * 16 + ln;
        const int mb = m0 + wr * 64 + mf * 16 + hi * 4;
        ushort4 o;
        o.x = f2bf(acc[mf][nf][0]); o.y = f2bf(acc[mf][nf][1]);
        o.z = f2bf(acc[mf][nf][2]); o.w = f2bf(acc[mf][nf][3]);
        *(ushort4*)(vt + (size_t)n * 2048 + mb) = o;
      }
  }
}

// ---------------- output projection + residual -> f32 d_out ----------------
__global__ __launch_bounds__(256) void wo_kernel(const unsigned short* __restrict__ ao,
                                                 const unsigned short* __restrict__ woT,
                                                 const float* __restrict__ x,
                                                 float* __restrict__ out) {
  __shared__ unsigned short lds[128 * 32 + 64 * 32];
  const int tid = threadIdx.x;
  const int m0 = blockIdx.y * 128, n0 = blockIdx.x * 64;
  f32x4_t acc[4][2] = {};
  const int cs = chunk_swz(tid);
  const unsigned short* aR0 = ao + (size_t)(m0 + (tid >> 2)) * 1024 + cs;
  const unsigned short* aR1 = aR0 + 64 * 1024;
  const unsigned short* bR0 = woT + (size_t)(n0 + (tid >> 2)) * 1024 + cs;
  gemm_loop<64>(aR0, aR1, bR0, nullptr, 1024, lds, tid, acc);
  const int lane = tid & 63, ln = lane & 15, hi = lane >> 4, wid = tid >> 6;
  const int wr = wid >> 1, wc = wid & 1;
#pragma unroll
  for (int mf = 0; mf < 4; ++mf)
#pragma unroll
    for (int nf = 0; nf < 2; ++nf)
#pragma unroll
      for (int r = 0; r < 4; ++r) {
        const int m = m0 + wr * 64 + mf * 16 + hi * 4 + r;
        const int n = n0 + wc * 32 + nf * 16 + ln;
        out[(size_t)m * 1024 + n] = acc[mf][nf][r] + x[(size_t)m * 1024 + n];
      }
}

// ---------------- flash attention, causal, head_dim 64 ----------------
__global__ __launch_bounds__(256) void attn_kernel(const unsigned short* __restrict__ qb,
                                                   const unsigned short* __restrict__ kbuf,
                                                   const unsigned short* __restrict__ vt,
                                                   unsigned short* __restrict__ ao) {
  __shared__ unsigned short kTl[4096];
  __shared__ unsigned short vTl[4096];
  __shared__ unsigned short pl[4][1024];
  const int tid = threadIdx.x;
  const int wid = tid >> 6, lane = tid & 63;
  const int ln = lane & 15, hi = lane >> 4;
  const int h = blockIdx.y;
  const int q0 = blockIdx.x * 64;
  const int q0w = q0 + wid * 16;

  const unsigned short* qrow = qb + (size_t)(q0w + ln) * 1024 + h * 64 + hi * 8;
  const bf16x8_t aq0 = *(const bf16x8_t*)(qrow);
  const bf16x8_t aq1 = *(const bf16x8_t*)(qrow + 32);

  const int str_r = tid >> 3, str_c = tid & 7;
  const int swc = (str_c ^ (str_r & 7)) * 8;
  const unsigned short* ksrc0 = kbuf + (size_t)str_r * 1024 + h * 64 + swc;
  const unsigned short* ksrc1 = kbuf + (size_t)(str_r + 32) * 1024 + h * 64 + swc;
  const unsigned short* vsrc0 = vt + (size_t)(h * 64 + str_r) * 2048 + swc;
  const unsigned short* vsrc1 = vt + (size_t)(h * 64 + str_r + 32) * 2048 + swc;
  char* kd0 = (char*)kTl + wid * 1024;
  char* kd1 = (char*)kTl + 4096 + wid * 1024;
  char* vd0 = (char*)vTl + wid * 1024;
  char* vd1 = (char*)vTl + 4096 + wid * 1024;

  float m_r[4], l_r[4];
  f32x4_t o_acc[4] = {};
#pragma unroll
  for (int r = 0; r < 4; ++r) { m_r[r] = -1e30f; l_r[r] = 0.f; }

  const int nkv = blockIdx.x + 1;
  for (int it = 0; it < nkv; ++it) {
    const int kv0 = it * 64;
    gload16(ksrc0 + (size_t)kv0 * 1024, kd0);
    gload16(ksrc1 + (size_t)kv0 * 1024, kd1);
    gload16(vsrc0 + kv0, vd0);
    gload16(vsrc1 + kv0, vd1);
    __syncthreads();

    float sc[4][4];
    __builtin_amdgcn_s_setprio(1);
#pragma unroll
    for (int cf = 0; cf < 4; ++cf) {
      const int row = cf * 16 + ln;
      const int swz = row & 7;
      const bf16x8_t b0 = *(const bf16x8_t*)((char*)kTl + row * 128 + ((hi ^ swz) * 16));
      const bf16x8_t b1 = *(const bf16x8_t*)((char*)kTl + row * 128 + (((4 + hi) ^ swz) * 16));
      f32x4_t zacc = {};
      zacc = mfma16(aq0, b0, zacc);
      zacc = mfma16(aq1, b1, zacc);
#pragma unroll
      for (int r = 0; r < 4; ++r) sc[cf][r] = zacc[r] * 0.125f;
    }
    __builtin_amdgcn_s_setprio(0);
    if (kv0 + 63 > q0w) {
#pragma unroll
      for (int cf = 0; cf < 4; ++cf)
#pragma unroll
        for (int r = 0; r < 4; ++r) {
          const int qg = q0w + hi * 4 + r;
          const int kg = kv0 + cf * 16 + ln;
          if (kg > qg) sc[cf][r] = -1e30f;
        }
    }
#pragma unroll
    for (int r = 0; r < 4; ++r) {
      float tm = fmaxf(fmaxf(sc[0][r], sc[1][r]), fmaxf(sc[2][r], sc[3][r]));
      tm = fmaxf(tm, __shfl_xor(tm, 1));
      tm = fmaxf(tm, __shfl_xor(tm, 2));
      tm = fmaxf(tm, __shfl_xor(tm, 4));
      tm = fmaxf(tm, __shfl_xor(tm, 8));
      const float mn = fmaxf(m_r[r], tm);
      const float alpha = __expf(m_r[r] - mn);
      float rsum = 0.f;
#pragma unroll
      for (int cf = 0; cf < 4; ++cf) {
        const float p = __expf(sc[cf][r] - mn);
        sc[cf][r] = p; rsum += p;
      }
      rsum += __shfl_xor(rsum, 1); rsum += __shfl_xor(rsum, 2);
      rsum += __shfl_xor(rsum, 4); rsum += __shfl_xor(rsum, 8);
      l_r[r] = l_r[r] * alpha + rsum;
      m_r[r] = mn;
#pragma unroll
      for (int df = 0; df < 4; ++df) o_acc[df][r] *= alpha;
    }
    unsigned short* pw = &pl[wid][0];
#pragma unroll
    for (int cf = 0; cf < 4; ++cf)
#pragma unroll
      for (int r = 0; r < 4; ++r) {
        const int qq = hi * 4 + r;
        const int kv = cf * 16 + ln;
        const int bo = (qq * 128 + kv * 2) ^ ((qq & 7) << 4);
        *(unsigned short*)((char*)pw + bo) = f2bf(sc[cf][r]);
      }
    __syncthreads();  // cross-lane P visibility + kTl/vTl ordering
    const bf16x8_t pa0 = *(const bf16x8_t*)((char*)pw + ((ln * 128 + hi * 16) ^ ((ln & 7) << 4)));
    const bf16x8_t pa1 = *(const bf16x8_t*)((char*)pw + ((ln * 128 + 64 + hi * 16) ^ ((ln & 7) << 4)));
    __builtin_amdgcn_s_setprio(1);
#pragma unroll
    for (int df = 0; df < 4; ++df) {
      const int d = df * 16 + ln;
      const int swz = d & 7;
      const bf16x8_t bv0 = *(const bf16x8_t*)((char*)vTl + d * 128 + ((hi ^ swz) * 16));
      const bf16x8_t bv1 = *(const bf16x8_t*)((char*)vTl + d * 128 + (((4 + hi) ^ swz) * 16));
      o_acc[df] = mfma16(pa0, bv0, o_acc[df]);
      o_acc[df] = mfma16(pa1, bv1, o_acc[df]);
    }
    __builtin_amdgcn_s_setprio(0);
    __syncthreads();
  }
#pragma unroll
  for (int df = 0; df < 4; ++df) {
    const int n = h * 64 + df * 16 + ln;
#pragma unroll
    for (int r = 0; r < 4; ++r) {
      const int m = q0w + hi * 4 + r;
      ao[(size_t)m * 1024 + n] = f2bf(o_acc[df][r] / l_r[r]);
    }
  }
}

// ---------------- gating: recompute LN2 in f32, top-2 of sigmoid, counts ----------------
__global__ __launch_bounds__(256) void gate_kernel(const float* __restrict__ x2, const float* __restrict__ g,
                                                   const float* __restrict__ b, const float* __restrict__ wg,
                                                   int2* __restrict__ te, float2* __restrict__ tw,
                                                   int* __restrict__ cnt) {
  const int tid = threadIdx.x, wid = tid >> 6, lane = tid & 63;
  const int t = blockIdx.x * 4 + wid;
  const float* row = x2 + (size_t)t * 1024;
  float vv[16];
#pragma unroll
  for (int i = 0; i < 4; ++i) *(float4*)&vv[i * 4] = *(const float4*)(row + lane * 16 + i * 4);
  float s = 0.f, s2 = 0.f;
#pragma unroll
  for (int j = 0; j < 16; ++j) { s += vv[j]; s2 += vv[j] * vv[j]; }
#pragma unroll
  for (int o = 1; o < 64; o <<= 1) { s += __shfl_xor(s, o); s2 += __shfl_xor(s2, o); }
  const float mu = s * 0.0009765625f;
  const float var = s2 * 0.0009765625f - mu * mu;
  const float rs = rsqrtf(var + 1e-5f);
  float acc[8] = {0.f, 0.f, 0.f, 0.f, 0.f, 0.f, 0.f, 0.f};
#pragma unroll
  for (int j = 0; j < 16; ++j) {
    const int d = lane * 16 + j;
    const float xv = (vv[j] - mu) * rs * g[d] + b[d];
    const float4 w0 = *(const float4*)(wg + d * 8);
    const float4 w1 = *(const float4*)(wg + d * 8 + 4);
    acc[0] += xv * w0.x; acc[1] += xv * w0.y; acc[2] += xv * w0.z; acc[3] += xv * w0.w;
    acc[4] += xv * w1.x; acc[5] += xv * w1.y; acc[6] += xv * w1.z; acc[7] += xv * w1.w;
  }
#pragma unroll
  for (int o = 1; o < 64; o <<= 1) {
#pragma unroll
    for (int e = 0; e < 8; ++e) acc[e] += __shfl_xor(acc[e], o);
  }
  if (lane == 0) {
    float sg[8];
#pragma unroll
    for (int e = 0; e < 8; ++e) sg[e] = 1.f / (1.f + __expf(-acc[e]));
    int e0 = 0;
#pragma unroll
    for (int e = 1; e < 8; ++e) if (sg[e] > sg[e0]) e0 = e;
    int e1 = (e0 == 0) ? 1 : 0;
#pragma unroll
    for (int e = 0; e < 8; ++e) if (e != e0 && sg[e] > sg[e1]) e1 = e;
    const float v0 = sg[e0], v1 = sg[e1];
    const float inv = 1.f / (v0 + v1 + 1e-9f);
    te[t] = make_int2(e0, e1);
    tw[t] = make_float2(v0 * inv, v1 * inv);
    atomicAdd(&cnt[e0], 1);
    atomicAdd(&cnt[e1], 1);
  }
}

__global__ void zero_counters(int* p) { if (threadIdx.x < 8) p[threadIdx.x] = 0; }

// ---------------- routing phase 2: 256-row tiles, padded offsets + metadata ----------------
__global__ __launch_bounds__(256) void g2_kernel(const int* __restrict__ cnt, int* __restrict__ slot_off,
                                                 int* __restrict__ tile_expert, int* __restrict__ tile_rowbase,
                                                 int* __restrict__ cursor, int* __restrict__ assign_token,
                                                 float* __restrict__ assign_w) {
  const int tid = threadIdx.x;
  for (int i = tid; i < 8192; i += 256) { assign_token[i] = -1; assign_w[i] = 0.f; }
  if (tid == 0) {
    int base = 0, tiles = 0;
    for (int e = 0; e < 8; ++e) {
      const int c = cnt[e];
      slot_off[e] = base;
      cursor[e] = 0;
      const int nt = (c + 255) >> 8;
      for (int i = 0; i < nt; ++i) {
        tile_expert[tiles] = e;
        tile_rowbase[tiles] = base + i * 256;
        ++tiles;
      }
      base += nt * 256;
    }
    for (; tiles < 40; ++tiles) tile_expert[tiles] = -1;
  }
}

// ---------------- routing phase 3: scatter assignments ----------------
__global__ __launch_bounds__(256) void g3_kernel(const int2* __restrict__ te, const float2* __restrict__ tw,
                                                 const int* __restrict__ slot_off, int* __restrict__ cursor,
                                                 int* __restrict__ assign_token, float* __restrict__ assign_w) {
  const int t = blockIdx.x * 256 + threadIdx.x;
  const int2 e = te[t];
  const float2 w = tw[t];
  const int s0 = slot_off[e.x] + atomicAdd(&cursor[e.x], 1);
  assign_token[s0] = t; assign_w[s0] = w.x;
  const int s1 = slot_off[e.y] + atomicAdd(&cursor[e.y], 1);
  assign_token[s1] = t; assign_w[s1] = w.y;
}

// ---- stage a 256x32 A tile (16KB) = 4 gload16 ----
DI void stageA4(const unsigned short* a0, const unsigned short* a1,
                const unsigned short* a2, const unsigned short* a3,
                int koff, char* Ab, int wid) {
  gload16(a0 + koff, Ab + wid * 1024);
  gload16(a1 + koff, Ab + 4096 + wid * 1024);
  gload16(a2 + koff, Ab + 8192 + wid * 1024);
  gload16(a3 + koff, Ab + 12288 + wid * 1024);
}

// ---- upgate helpers (BM=256) ----
DI void ug_write_b(char* Bn, const int* boff, const float4& q0, const float4& q1,
                   const float4& q2, const float4& q3) {
  const float* q0p = (const float*)&q0; const float* q1p = (const float*)&q1;
  const float* q2p = (const float*)&q2; const float* q3p = (const float*)&q3;
#pragma unroll
  for (int i = 0; i < 4; ++i) {
    uint2 w;
    w.x = pk2(q0p[i], q1p[i]);
    w.y = pk2(q2p[i], q3p[i]);
    *(uint2*)(Bn + boff[i]) = w;
  }
}

DI void ug_mfma256(const unsigned short* A, const char* Bb, int wr, int wc, int ln, int hi,
                   f32x4_t (&accg)[8][2], f32x4_t (&accu)[8][2]) {
  bf16x8_t af[8];
#pragma unroll
  for (int mf = 0; mf < 8; ++mf)
    af[mf] = frag(A, wr * 128 + mf * 16 + ln, hi);
  __builtin_amdgcn_s_setprio(1);
#pragma unroll
  for (int nf = 0; nf < 2; ++nf) {
    const int nrow = wc * 32 + nf * 16 + ln;
    int bo = nrow * 64 + hi * 16;
    bo ^= ((nrow >> 2) & 7) << 4;
    const bf16x8_t bg = *(const bf16x8_t*)(Bb + bo);
    const bf16x8_t bu = *(const bf16x8_t*)(Bb + 4096 + bo);
#pragma unroll
    for (int mf = 0; mf < 8; ++mf) {
      accg[mf][nf] = mfma16(af[mf], bg, accg[mf][nf]);
      accu[mf][nf] = mfma16(af[mf], bu, accu[mf][nf]);
    }
  }
  __builtin_amdgcn_s_setprio(0);
}

// ---------------- MoE up+gate: BM=256, A-first issue order (race-free 2-deep B) ----------
__global__ __launch_bounds__(256, 2) void upgate_kernel(const unsigned short* __restrict__ h2,
                                                        const float* __restrict__ w_eg, const float* __restrict__ w_eu,
                                                        const int* __restrict__ tile_expert,
                                                        const int* __restrict__ tile_rowbase,
                                                        const int* __restrict__ assign_token,
                                                        unsigned short* __restrict__ act) {
  const int by = blockIdx.y;
  const int e = tile_expert[by];
  if (e < 0) return;
  const int n0 = blockIdx.x * 64;
  const int rowbase = tile_rowbase[by];
  const int tid = threadIdx.x;
  __shared__ unsigned short lds[2 * 8192 + 2 * 4096];  // A dbuf 2x16KB, B dbuf 2x8KB
  char* A0 = (char*)lds;
  char* A1 = (char*)lds + 16384;
  char* B0 = (char*)lds + 32768;
  char* B1 = (char*)lds + 40960;
  const int wid = tid >> 6, lane = tid & 63, ln = lane & 15, hi = lane >> 4;
  const int wr = wid >> 1, wc = wid & 1;
  const int r0s = rowbase + (tid >> 2);
  int tk0 = assign_token[r0s];        tk0 = tk0 < 0 ? 0 : tk0;
  int tk1 = assign_token[r0s + 64];   tk1 = tk1 < 0 ? 0 : tk1;
  int tk2 = assign_token[r0s + 128];  tk2 = tk2 < 0 ? 0 : tk2;
  int tk3 = assign_token[r0s + 192];  tk3 = tk3 < 0 ? 0 : tk3;
  const int cs = chunk_swz(tid);
  const unsigned short* aR0 = h2 + (size_t)tk0 * 1024 + cs;
  const unsigned short* aR1 = h2 + (size_t)tk1 * 1024 + cs;
  const unsigned short* aR2 = h2 + (size_t)tk2 * 1024 + cs;
  const unsigned short* aR3 = h2 + (size_t)tk3 * 1024 + cs;
  const int mat = tid >> 7;
  const int blk = tid & 127;
  const int kb = (blk >> 4) * 4;
  const int nb = (blk & 15) * 4;
  const float* bsrc = (mat ? w_eu : w_eg) + (size_t)e * 1024 * 4096 + (size_t)kb * 4096 + n0 + nb;
  int boff[4];
#pragma unroll
  for (int i = 0; i < 4; ++i) {
    const int n = nb + i;
    int bo = mat * 4096 + n * 64 + kb * 2;
    bo ^= ((n >> 2) & 7) << 4;
    boff[i] = bo;
  }
  f32x4_t accg[8][2] = {};
  f32x4_t accu[8][2] = {};
  float4 qA0, qA1, qA2, qA3, qB0, qB1, qB2, qB3;
  // ---- prologue: A(0)->A0; B(0)->regs; write B0 (drains A(0) too, FIFO); B(1)->qA ----
  stageA4(aR0, aR1, aR2, aR3, 0, A0, wid);
  qB0 = *(const float4*)(bsrc);
  qB1 = *(const float4*)(bsrc + 4096);
  qB2 = *(const float4*)(bsrc + 8192);
  qB3 = *(const float4*)(bsrc + 12288);
  __builtin_amdgcn_sched_barrier(0);
  ug_write_b(B0, boff, qB0, qB1, qB2, qB3);
  {
    const float* bs = bsrc + (size_t)32 * 4096;
    qA0 = *(const float4*)(bs);
    qA1 = *(const float4*)(bs + 4096);
    qA2 = *(const float4*)(bs + 8192);
    qA3 = *(const float4*)(bs + 12288);
  }
  asm volatile("s_waitcnt lgkmcnt(0)" ::: "memory");
  __builtin_amdgcn_sched_barrier(0);
  __builtin_amdgcn_s_barrier();
  // ---- main: t = 0..29 (15 pairs) ----
  for (int p = 0; p < 15; ++p) {
    {  // even t=2p: compute A0/B0; stage A(t+1)->A1; load B(t+2)->qB
      const int t = 2 * p;
      stageA4(aR0, aR1, aR2, aR3, (t + 1) * 32, A1, wid);
      const float* bs = bsrc + (size_t)(t + 2) * 32 * 4096;
      qB0 = *(const float4*)(bs);
      qB1 = *(const float4*)(bs + 4096);
      qB2 = *(const float4*)(bs + 8192);
      qB3 = *(const float4*)(bs + 12288);
      __builtin_amdgcn_sched_barrier(0);
      ug_write_b(B1, boff, qA0, qA1, qA2, qA3);   // implied vmcnt(8): keeps A(t+1)+B(t+2)
      ug_mfma256((const unsigned short*)A0, B0, wr, wc, ln, hi, accg, accu);
      asm volatile("s_waitcnt vmcnt(4)" ::: "memory");  // retire A(t+1)x4; keep B(t+2)x4
      __builtin_amdgcn_sched_barrier(0);
      asm volatile("s_waitcnt lgkmcnt(0)" ::: "memory");
      __builtin_amdgcn_sched_barrier(0);
      __builtin_amdgcn_s_barrier();
    }
    {  // odd t=2p+1: compute A1/B1
      const int t = 2 * p + 1;
      stageA4(aR0, aR1, aR2, aR3, (t + 1) * 32, A0, wid);
      const float* bs = bsrc + (size_t)(t + 2) * 32 * 4096;
      qA0 = *(const float4*)(bs);
      qA1 = *(const float4*)(bs + 4096);
      qA2 = *(const float4*)(bs + 8192);
      qA3 = *(const float4*)(bs + 12288);
      __builtin_amdgcn_sched_barrier(0);
      ug_write_b(B0, boff, qB0, qB1, qB2, qB3);
      ug_mfma256((const unsigned short*)A1, B1, wr, wc, ln, hi, accg, accu);
      asm volatile("s_waitcnt vmcnt(4)" ::: "memory");
      __builtin_amdgcn_sched_barrier(0);
      asm volatile("s_waitcnt lgkmcnt(0)" ::: "memory");
      __builtin_amdgcn_sched_barrier(0);
      __builtin_amdgcn_s_barrier();
    }
  }
  // ---- t=30 (A0/B0): stage A(31)->A1; write B(31) from qA; drain all ----
  stageA4(aR0, aR1, aR2, aR3, 31 * 32, A1, wid);
  __builtin_amdgcn_sched_barrier(0);
  ug_write_b(B1, boff, qA0, qA1, qA2, qA3);   // implied vmcnt(4): keeps A(31)
  ug_mfma256((const unsigned short*)A0, B0, wr, wc, ln, hi, accg, accu);
  asm volatile("s_waitcnt vmcnt(0)" ::: "memory");
  __builtin_amdgcn_sched_barrier(0);
  asm volatile("s_waitcnt lgkmcnt(0)" ::: "memory");
  __builtin_amdgcn_sched_barrier(0);
  __builtin_amdgcn_s_barrier();
  // ---- t=31: MFMA only ----
  ug_mfma256((const unsigned short*)A1, B1, wr, wc, ln, hi, accg, accu);
#pragma unroll
  for (int mf = 0; mf < 8; ++mf)
#pragma unroll
    for (int nf = 0; nf < 2; ++nf)
#pragma unroll
      for (int r = 0; r < 4; ++r) {
        const int m = wr * 128 + mf * 16 + hi * 4 + r;
        const int n = n0 + wc * 32 + nf * 16 + ln;
        const float gv = accg[mf][nf][r], uv = accu[mf][nf][r];
        const float val = gv / (1.f + __expf(-gv)) * uv;
        act[(size_t)(rowbase + m) * 4096 + n] = f2bf(val);
      }
}

// ---- down helpers (BM=256) ----
DI void dn_write_b(char* Bn, const int* boff, const float4& q0, const float4& q1) {
  const float* q0p = (const float*)&q0; const float* q1p = (const float*)&q1;
#pragma unroll
  for (int i = 0; i < 4; ++i)
    *(uint32_t*)(Bn + boff[i]) = pk2(q0p[i], q1p[i]);
}

DI void dn_mfma256(const unsigned short* A, const char* Bb, int wr, int wc, int ln, int hi,
                   f32x4_t (&acc)[8][2]) {
  bf16x8_t af[8];
#pragma unroll
  for (int mf = 0; mf < 8; ++mf)
    af[mf] = frag(A, wr * 128 + mf * 16 + ln, hi);
  __builtin_amdgcn_s_setprio(1);
#pragma unroll
  for (int nf = 0; nf < 2; ++nf) {
    const int nrow = wc * 32 + nf * 16 + ln;
    int bo = nrow * 64 + hi * 16;
    bo ^= ((nrow >> 2) & 7) << 4;
    const bf16x8_t bb = *(const bf16x8_t*)(Bb + bo);
#pragma unroll
    for (int mf = 0; mf < 8; ++mf)
      acc[mf][nf] = mfma16(af[mf], bb, acc[mf][nf]);
  }
  __builtin_amdgcn_s_setprio(0);
}

// ---------------- MoE down: BM=256 (halves B re-reads), split-K x4, 2-deep A-first --------
// grid (16 n0, 24 tiles, 4 kz); each block: 256 rows x 64 cols, K-slice of 1024 (32 steps).
// FIFO per iter t: [start: B(t+1)x2] +A(t+1)x4 +B(t+2)x2 ; ds_write B(t+1) => implied vmcnt(6);
// MFMA(t); vmcnt(2) retires A(t+1)x4, keeps B(t+2)x2; waits precede barrier (race-safe).
__global__ __launch_bounds__(256, 2) void down_kernel(const unsigned short* __restrict__ act,
                                                      const float* __restrict__ w_ed,
                                                      const int* __restrict__ tile_expert,
                                                      const int* __restrict__ tile_rowbase,
                                                      const int* __restrict__ assign_token,
                                                      const float* __restrict__ assign_w,
                                                      float* __restrict__ out) {
  const int by = blockIdx.y;
  const int e = tile_expert[by];
  if (e < 0) return;
  const int rowbase = tile_rowbase[by];
  const int n0 = blockIdx.x * 64;
  const int kz = blockIdx.z * 1024;
  const int tid = threadIdx.x;
  __shared__ unsigned short lds[2 * 8192 + 2 * 2048];  // A dbuf 2x16KB, B dbuf 2x4KB
  char* A0 = (char*)lds;
  char* A1 = (char*)lds + 16384;
  char* B0 = (char*)lds + 32768;
  char* B1 = (char*)lds + 36864;
  const int wid = tid >> 6, lane = tid & 63, ln = lane & 15, hi = lane >> 4;
  const int wr = wid >> 1, wc = wid & 1;
  const int cs = chunk_swz(tid);
  const unsigned short* aR0 = act + (size_t)(rowbase + (tid >> 2)) * 4096 + kz + cs;
  const unsigned short* aR1 = aR0 + (size_t)64 * 4096;
  const unsigned short* aR2 = aR0 + (size_t)128 * 4096;
  const unsigned short* aR3 = aR0 + (size_t)192 * 4096;
  const int nb = (tid & 15) * 4;
  const int kb2 = (tid >> 4) * 2;
  const float* bsrc = w_ed + (size_t)e * 4096 * 1024 + (size_t)(kz + kb2) * 1024 + n0 + nb;
  int boff[4];
#pragma unroll
  for (int i = 0; i < 4; ++i) {
    const int n = nb + i;
    int bo = n * 64 + kb2 * 2;
    bo ^= ((n >> 2) & 7) << 4;
    boff[i] = bo;
  }
  f32x4_t acc[8][2] = {};
  float4 qA0, qA1, qB0, qB1;
  // ---- prologue ----
  stageA4(aR0, aR1, aR2, aR3, 0, A0, wid);
  qB0 = *(const float4*)(bsrc);
  qB1 = *(const float4*)(bsrc + 1024);
  __builtin_amdgcn_sched_barrier(0);
  dn_write_b(B0, boff, qB0, qB1);   // implied wait drains A(0)x4 too (older in FIFO)
  {
    const float* bs = bsrc + (size_t)32 * 1024;
    qA0 = *(const float4*)(bs);
    qA1 = *(const float4*)(bs + 1024);
  }
  asm volatile("s_waitcnt lgkmcnt(0)" ::: "memory");
  __builtin_amdgcn_sched_barrier(0);
  __builtin_amdgcn_s_barrier();
  // ---- main: t = 0..29 (15 pairs) ----
  for (int p = 0; p < 15; ++p) {
    {  // even t=2p: compute A0/B0
      const int t = 2 * p;
      stageA4(aR0, aR1, aR2, aR3, (t + 1) * 32, A1, wid);
      const float* bs = bsrc + (size_t)(t + 2) * 32 * 1024;
      qB0 = *(const float4*)(bs);
      qB1 = *(const float4*)(bs + 1024);
      __builtin_amdgcn_sched_barrier(0);
      dn_write_b(B1, boff, qA0, qA1);   // implied vmcnt(6): keeps A(t+1)x4 + B(t+2)x2
      dn_mfma256((const unsigned short*)A0, B0, wr, wc, ln, hi, acc);
      asm volatile("s_waitcnt vmcnt(2)" ::: "memory");  // retire A(t+1)x4; keep B(t+2)x2
      __builtin_amdgcn_sched_barrier(0);
      asm volatile("s_waitcnt lgkmcnt(0)" ::: "memory");
      __builtin_amdgcn_sched_barrier(0);
      __builtin_amdgcn_s_barrier();
    }
    {  // odd t=2p+1: compute A1/B1
      const int t = 2 * p + 1;
      stageA4(aR0, aR1, aR2, aR3, (t + 1) * 32, A0, wid);
      const float* bs = bsrc + (size_t)(t + 2) * 32 * 1024;
      qA0 = *(const float4*)(bs);
      qA1 = *(const float4*)(bs + 1024);
      __builtin_amdgcn_sched_barrier(0);
      dn_write_b(B0, boff, qB0, qB1);
      dn_mfma256((const unsigned short*)A1, B1, wr, wc, ln, hi, acc);
      asm volatile("s_waitcnt vmcnt(2)" ::: "memory");
      __builtin_amdgcn_sched_barrier(0);
      asm volatile("s_waitcnt lgkmcnt(0)" ::: "memory");
      __builtin_amdgcn_sched_barrier(0);
      __builtin_amdgcn_s_barrier();
    }
  }
  // ---- t=30: stage A(31); write B(31) from qA; drain ----
  stageA4(aR0, aR1, aR2, aR3, 31 * 32, A1, wid);
  __builtin_amdgcn_sched_barrier(0);
  dn_write_b(B1, boff, qA0, qA1);
  dn_mfma256((const unsigned short*)A0, B0, wr, wc, ln, hi, acc);
  asm volatile("s_waitcnt vmcnt(0)" ::: "memory");
  __builtin_amdgcn_sched_barrier(0);
  asm volatile("s_waitcnt lgkmcnt(0)" ::: "memory");
  __builtin_amdgcn_sched_barrier(0);
  __builtin_amdgcn_s_barrier();
  // ---- t=31 ----
  dn_mfma256((const unsigned short*)A1, B1, wr, wc, ln, hi, acc);
#pragma unroll
  for (int mf = 0; mf < 8; ++mf)
#pragma unroll
    for (int r = 0; r < 4; ++r) {
      const int m = wr * 128 + mf * 16 + hi * 4 + r;
      const int slot = rowbase + m;
      const int tk = assign_token[slot];
      if (tk >= 0) {
        const float w = assign_w[slot];
#pragma unroll
        for (int nf = 0; nf < 2; ++nf) {
          const int n = n0 + wc * 32 + nf * 16 + ln;
          atomicAdd(out + (size_t)tk * 1024 + n, acc[mf][nf][r] * w);
        }
      }
    }
}

// ---------------- host launcher ----------------
extern "C" void kernel_launch(void* const* d_in, const int* in_sizes, int n_in,
                              void* d_out, int out_size, void* d_ws, size_t ws_size,
                              hipStream_t stream) {
  (void)in_sizes; (void)n_in; (void)out_size;
  const float* x    = (const float*)d_in[0];
  const float* ln1g = (const float*)d_in[1];
  const float* ln1b = (const float*)d_in[2];
  const float* wq   = (const float*)d_in[3];
  const float* wk   = (const float*)d_in[4];
  const float* wv   = (const float*)d_in[5];
  const float* wo   = (const float*)d_in[6];
  const float* ln2g = (const float*)d_in[7];
  const float* ln2b = (const float*)d_in[8];
  const float* wg   = (const float*)d_in[9];
  const float* weg  = (const float*)d_in[10];
  const float* weu  = (const float*)d_in[11];
  const float* wed  = (const float*)d_in[12];
  float* out = (float*)d_out;
  char* ws = (char*)d_ws;

  const size_t MB = (size_t)1 << 20;
  if (ws_size < 86 * MB) return;
  unsigned short* wqT = (unsigned short*)(ws + 0 * MB);
  unsigned short* wkT = (unsigned short*)(ws + 2 * MB);
  unsigned short* wvT = (unsigned short*)(ws + 4 * MB);
  unsigned short* woT = (unsigned short*)(ws + 6 * MB);
  unsigned short* h1  = (unsigned short*)(ws + 8 * MB);
  unsigned short* qb  = (unsigned short*)(ws + 12 * MB);
  unsigned short* kbf = (unsigned short*)(ws + 16 * MB);
  unsigned short* vt  = (unsigned short*)(ws + 20 * MB);
  unsigned short* ao  = (unsigned short*)(ws + 24 * MB);
  unsigned short* h2  = (unsigned short*)(ws + 28 * MB);
  unsigned short* act = (unsigned short*)(ws + 32 * MB);  // 6144*4096*2 = 48MiB (52MB slot)
  int2*   te = (int2*)(ws + 84 * MB);
  float2* tw = (float2*)(ws + 84 * MB + 16384);
  int*  meta = (int*)(ws + 84 * MB + 32768);
  int* cnt = meta;
  int* cursor = meta + 8;
  int* slot_off = meta + 16;
  int* tile_expert = meta + 24;
  int* tile_rowbase = meta + 64;
  int*   assign_token = (int*)(ws + 84 * MB + 36864);
  float* assign_w     = (float*)(ws + 84 * MB + 36864 + 32768);

  zero_counters<<<1, 64, 0, stream>>>(cnt);
  transpose_cvt4<<<dim3(16, 16, 4), 256, 0, stream>>>(wq, wk, wv, wo, wqT, wkT, wvT, woT);
  ln_kernel<<<2048, 256, 0, stream>>>(x, ln1g, ln1b, h1);
  qkv_kernel<<<dim3(8, 16, 3), 256, 0, stream>>>(h1, wqT, wkT, wvT, qb, kbf, vt);
  attn_kernel<<<dim3(32, 16), 256, 0, stream>>>(qb, kbf, vt, ao);
  wo_kernel<<<dim3(16, 16), 256, 0, stream>>>(ao, woT, x, out);
  ln_kernel<<<2048, 256, 0, stream>>>(out, ln2g, ln2b, h2);
  gate_kernel<<<512, 256, 0, stream>>>(out, ln2g, ln2b, wg, te, tw, cnt);
  g2_kernel<<<1, 256, 0, stream>>>(cnt, slot_off, tile_expert, tile_rowbase, cursor, assign_token, assign_w);
  g3_kernel<<<8, 256, 0, stream>>>(te, tw, slot_off, cursor, assign_token, assign_w);
  upgate_kernel<<<dim3(64, 24), 256, 0, stream>>>(h2, weg, weu, tile_expert, tile_rowbase, assign_token, act);
  down_kernel<<<dim3(16, 24, 4), 256, 0, stream>>>(act, wed, tile_expert, tile_rowbase, assign_token, assign_w, out);
}

// Round 14
// 486.768 us; speedup vs baseline: 1.0415x; 1.0415x over previous
//
#include <hip/hip_runtime.h>
#include <hip/hip_bf16.h>
#include <stdint.h>

#define DI __device__ __forceinline__

typedef short bf16x8_t __attribute__((ext_vector_type(8)));
typedef float f32x4_t __attribute__((ext_vector_type(4)));

DI unsigned short f2bf(float f) {
  __hip_bfloat16 h = __float2bfloat16(f);
  unsigned short u;
  __builtin_memcpy(&u, &h, 2);
  return u;
}

// pair f32 -> packed 2xbf16 (compiler emits v_cvt_pk_bf16_f32)
DI uint32_t pk2(float a, float b) {
  return (uint32_t)f2bf(a) | ((uint32_t)f2bf(b) << 16);
}

DI f32x4_t mfma16(bf16x8_t a, bf16x8_t b, f32x4_t c) {
  return __builtin_amdgcn_mfma_f32_16x16x32_bf16(a, b, c, 0, 0, 0);
}

DI void gload16(const void* g, void* l) {
  __builtin_amdgcn_global_load_lds(
      (const __attribute__((address_space(1))) uint32_t*)g,
      (__attribute__((address_space(3))) uint32_t*)l, 16, 0, 0);
}

// A/B tile fragment read with chunk swizzle matching pre-swizzled global source:
// lds[row][chunk ^ ((row>>1)&3)], tile row = 32 shorts (64B), chunk = 8 shorts (16B)
DI bf16x8_t frag(const unsigned short* base, int row, int hi) {
  return *(const bf16x8_t*)&base[row * 32 + ((hi ^ ((row >> 1) & 3)) * 8)];
}
// per-lane source chunk offset (in shorts) for gload16 A/B staging
DI int chunk_swz(int tid) { return ((tid & 3) ^ ((tid >> 3) & 3)) * 8; }

// ---------------- fused transpose + f32->bf16 for 4 square matrices (z selects) ----------
__global__ __launch_bounds__(256) void transpose_cvt4(const float* __restrict__ s0, const float* __restrict__ s1,
                                                      const float* __restrict__ s2, const float* __restrict__ s3,
                                                      unsigned short* __restrict__ d0, unsigned short* __restrict__ d1,
                                                      unsigned short* __restrict__ d2, unsigned short* __restrict__ d3) {
  __shared__ float tile[64][65];
  const int z = blockIdx.z;
  const float* in = (z == 0) ? s0 : (z == 1) ? s1 : (z == 2) ? s2 : s3;
  unsigned short* out = (z == 0) ? d0 : (z == 1) ? d1 : (z == 2) ? d2 : d3;
  const int tid = threadIdx.x;
  const int tx = tid & 15, ty = tid >> 4;
  const int r0 = blockIdx.y * 64, c0 = blockIdx.x * 64;
#pragma unroll
  for (int i = 0; i < 4; ++i) {
    const int r = ty + i * 16;
    const float4 v = *(const float4*)(in + (size_t)(r0 + r) * 1024 + c0 + tx * 4);
    tile[r][tx * 4 + 0] = v.x; tile[r][tx * 4 + 1] = v.y;
    tile[r][tx * 4 + 2] = v.z; tile[r][tx * 4 + 3] = v.w;
  }
  __syncthreads();
#pragma unroll
  for (int i = 0; i < 4; ++i) {
    const int r = ty + i * 16;
    ushort4 o;
    o.x = f2bf(tile[tx * 4 + 0][r]); o.y = f2bf(tile[tx * 4 + 1][r]);
    o.z = f2bf(tile[tx * 4 + 2][r]); o.w = f2bf(tile[tx * 4 + 3][r]);
    *(ushort4*)(out + (size_t)(c0 + r) * 1024 + r0 + tx * 4) = o;
  }
}

// ---------------- LayerNorm f32 -> bf16 ----------------
__global__ __launch_bounds__(256) void ln_kernel(const float* __restrict__ x, const float* __restrict__ g,
                                                 const float* __restrict__ b, unsigned short* __restrict__ out) {
  const int row = blockIdx.x, tid = threadIdx.x;
  const int wid = tid >> 6, lane = tid & 63;
  const float4 v = *(const float4*)(x + (size_t)row * 1024 + tid * 4);
  float s = v.x + v.y + v.z + v.w;
  float s2 = v.x * v.x + v.y * v.y + v.z * v.z + v.w * v.w;
#pragma unroll
  for (int o = 1; o < 64; o <<= 1) { s += __shfl_xor(s, o); s2 += __shfl_xor(s2, o); }
  __shared__ float red[8];
  if (lane == 0) { red[wid] = s; red[4 + wid] = s2; }
  __syncthreads();
  const float ts = red[0] + red[1] + red[2] + red[3];
  const float ts2 = red[4] + red[5] + red[6] + red[7];
  const float mu = ts * 0.0009765625f;
  const float var = ts2 * 0.0009765625f - mu * mu;
  const float rs = rsqrtf(var + 1e-5f);
  const float4 gg = *(const float4*)(g + tid * 4);
  const float4 bb = *(const float4*)(b + tid * 4);
  ushort4 o4;
  o4.x = f2bf((v.x - mu) * rs * gg.x + bb.x);
  o4.y = f2bf((v.y - mu) * rs * gg.y + bb.y);
  o4.z = f2bf((v.z - mu) * rs * gg.z + bb.z);
  o4.w = f2bf((v.w - mu) * rs * gg.w + bb.w);
  *(ushort4*)(out + (size_t)row * 1024 + tid * 4) = o4;
}

// ---------------- generic bf16 GEMM core: BM=128, BK=32, 256 thr, waves 2x2 ----------------
template<int BN>
DI void gemm_loop(const unsigned short* aR0, const unsigned short* aR1,
                  const unsigned short* bR0, const unsigned short* bR1,
                  const int K, unsigned short* lds, const int tid,
                  f32x4_t (&acc)[4][BN / 32]) {
  constexpr int NF = BN / 32;
  unsigned short* ldsA = lds;
  unsigned short* ldsB = lds + 4096;  // 128*32
  const int wid = tid >> 6, lane = tid & 63, ln = lane & 15, hi = lane >> 4;
  const int wr = wid >> 1, wc = wid & 1;
  char* dstA0 = (char*)ldsA + wid * 1024;
  char* dstA1 = (char*)ldsA + 4096 + wid * 1024;
  char* dstB0 = (char*)ldsB + wid * 1024;
  char* dstB1 = (char*)ldsB + 4096 + wid * 1024;
  for (int k0 = 0; k0 < K; k0 += 32) {
    gload16(aR0 + k0, dstA0);
    gload16(aR1 + k0, dstA1);
    gload16(bR0 + k0, dstB0);
    if constexpr (BN == 128) gload16(bR1 + k0, dstB1);
    __syncthreads();
    bf16x8_t af[4];
#pragma unroll
    for (int mf = 0; mf < 4; ++mf)
      af[mf] = frag(ldsA, wr * 64 + mf * 16 + ln, hi);
    __builtin_amdgcn_s_setprio(1);
#pragma unroll
    for (int nf = 0; nf < NF; ++nf) {
      bf16x8_t bfr = frag(ldsB, wc * (BN / 2) + nf * 16 + ln, hi);
#pragma unroll
      for (int mf = 0; mf < 4; ++mf)
        acc[mf][nf] = mfma16(af[mf], bfr, acc[mf][nf]);
    }
    __builtin_amdgcn_s_setprio(0);
    __syncthreads();
  }
}

// ---------------- QKV projections (z = 0:Q, 1:K, 2:V-transposed) ----------------
__global__ __launch_bounds__(256) void qkv_kernel(const unsigned short* __restrict__ h1,
                                                  const unsigned short* __restrict__ wqT,
                                                  const unsigned short* __restrict__ wkT,
                                                  const unsigned short* __restrict__ wvT,
                                                  unsigned short* __restrict__ qb,
                                                  unsigned short* __restrict__ kbf,
                                                  unsigned short* __restrict__ vt) {
  __shared__ unsigned short lds[128 * 32 + 128 * 32];
  const int tid = threadIdx.x;
  const int z = blockIdx.z;
  const unsigned short* BT = (z == 0) ? wqT : (z == 1) ? wkT : wvT;
  const int m0 = blockIdx.y * 128, n0 = blockIdx.x * 128;
  f32x4_t acc[4][4] = {};
  const int cs = chunk_swz(tid);
  const unsigned short* aR0 = h1 + (size_t)(m0 + (tid >> 2)) * 1024 + cs;
  const unsigned short* aR1 = aR0 + 64 * 1024;
  const unsigned short* bR0 = BT + (size_t)(n0 + (tid >> 2)) * 1024 + cs;
  const unsigned short* bR1 = bR0 + 64 * 1024;
  gemm_loop<128>(aR0, aR1, bR0, bR1, 1024, lds, tid, acc);
  const int lane = tid & 63, ln = lane & 15, hi = lane >> 4, wid = tid >> 6;
  const int wr = wid >> 1, wc = wid & 1;
  if (z < 2) {
    unsigned short* o = z ? kbf : qb;
#pragma unroll
    for (int mf = 0; mf < 4; ++mf)
#pragma unroll
      for (int nf = 0; nf < 4; ++nf)
#pragma unroll
        for (int r = 0; r < 4; ++r) {
          const int m = m0 + wr * 64 + mf * 16 + hi * 4 + r;
          const int n = n0 + wc * 64 + nf * 16 + ln;
          o[(size_t)m * 1024 + n] = f2bf(acc[mf][nf][r]);
        }
  } else {
#pragma unroll
    for (int mf = 0; mf < 4; ++mf)
#pragma unroll
      for (int nf = 0; nf < 4; ++nf) {
        const int n = n0 + wc * 64 + nf * 16 + ln;
        const int mb = m0 + wr * 64 + mf * 16 + hi * 4;
        ushort4 o;
        o.x = f2bf(acc[mf][nf][0]); o.y = f2bf(acc[mf][nf][1]);
        o.z = f2bf(acc[mf][nf][2]); o.w = f2bf(acc[mf][nf][3]);
        *(ushort4*)(vt + (size_t)n * 2048 + mb) = o;
      }
  }
}

// ---------------- output projection + residual -> f32 d_out ----------------
__global__ __launch_bounds__(256) void wo_kernel(const unsigned short* __restrict__ ao,
                                                 const unsigned short* __restrict__ woT,
                                                 const float* __restrict__ x,
                                                 float* __restrict__ out) {
  __shared__ unsigned short lds[128 * 32 + 64 * 32];
  const int tid = threadIdx.x;
  const int m0 = blockIdx.y * 128, n0 = blockIdx.x * 64;
  f32x4_t acc[4][2] = {};
  const int cs = chunk_swz(tid);
  const unsigned short* aR0 = ao + (size_t)(m0 + (tid >> 2)) * 1024 + cs;
  const unsigned short* aR1 = aR0 + 64 * 1024;
  const unsigned short* bR0 = woT + (size_t)(n0 + (tid >> 2)) * 1024 + cs;
  gemm_loop<64>(aR0, aR1, bR0, nullptr, 1024, lds, tid, acc);
  const int lane = tid & 63, ln = lane & 15, hi = lane >> 4, wid = tid >> 6;
  const int wr = wid >> 1, wc = wid & 1;
#pragma unroll
  for (int mf = 0; mf < 4; ++mf)
#pragma unroll
    for (int nf = 0; nf < 2; ++nf)
#pragma unroll
      for (int r = 0; r < 4; ++r) {
        const int m = m0 + wr * 64 + mf * 16 + hi * 4 + r;
        const int n = n0 + wc * 32 + nf * 16 + ln;
        out[(size_t)m * 1024 + n] = acc[mf][nf][r] + x[(size_t)m * 1024 + n];
      }
}

// ---------------- flash attention, causal, head_dim 64 ----------------
// Load-balance: co-resident block pair (x,h) / (x,h+8) maps to complementary q-tiles
// (qi and 31-qi) so每 CU's two blocks sum to a constant 33 KV-iterations.
__global__ __launch_bounds__(256) void attn_kernel(const unsigned short* __restrict__ qb,
                                                   const unsigned short* __restrict__ kbuf,
                                                   const unsigned short* __restrict__ vt,
                                                   unsigned short* __restrict__ ao) {
  __shared__ unsigned short kTl[4096];
  __shared__ unsigned short vTl[4096];
  __shared__ unsigned short pl[4][1024];
  const int tid = threadIdx.x;
  const int wid = tid >> 6, lane = tid & 63;
  const int ln = lane & 15, hi = lane >> 4;
  const int h = blockIdx.y;
  const int qi = (h < 8) ? blockIdx.x : (31 - blockIdx.x);
  const int q0 = qi * 64;
  const int q0w = q0 + wid * 16;

  const unsigned short* qrow = qb + (size_t)(q0w + ln) * 1024 + h * 64 + hi * 8;
  const bf16x8_t aq0 = *(const bf16x8_t*)(qrow);
  const bf16x8_t aq1 = *(const bf16x8_t*)(qrow + 32);

  const int str_r = tid >> 3, str_c = tid & 7;
  const int swc = (str_c ^ (str_r & 7)) * 8;
  const unsigned short* ksrc0 = kbuf + (size_t)str_r * 1024 + h * 64 + swc;
  const unsigned short* ksrc1 = kbuf + (size_t)(str_r + 32) * 1024 + h * 64 + swc;
  const unsigned short* vsrc0 = vt + (size_t)(h * 64 + str_r) * 2048 + swc;
  const unsigned short* vsrc1 = vt + (size_t)(h * 64 + str_r + 32) * 2048 + swc;
  char* kd0 = (char*)kTl + wid * 1024;
  char* kd1 = (char*)kTl + 4096 + wid * 1024;
  char* vd0 = (char*)vTl + wid * 1024;
  char* vd1 = (char*)vTl + 4096 + wid * 1024;

  float m_r[4], l_r[4];
  f32x4_t o_acc[4] = {};
#pragma unroll
  for (int r = 0; r < 4; ++r) { m_r[r] = -1e30f; l_r[r] = 0.f; }

  const int nkv = qi + 1;
  for (int it = 0; it < nkv; ++it) {
    const int kv0 = it * 64;
    gload16(ksrc0 + (size_t)kv0 * 1024, kd0);
    gload16(ksrc1 + (size_t)kv0 * 1024, kd1);
    gload16(vsrc0 + kv0, vd0);
    gload16(vsrc1 + kv0, vd1);
    __syncthreads();

    float sc[4][4];
    __builtin_amdgcn_s_setprio(1);
#pragma unroll
    for (int cf = 0; cf < 4; ++cf) {
      const int row = cf * 16 + ln;
      const int swz = row & 7;
      const bf16x8_t b0 = *(const bf16x8_t*)((char*)kTl + row * 128 + ((hi ^ swz) * 16));
      const bf16x8_t b1 = *(const bf16x8_t*)((char*)kTl + row * 128 + (((4 + hi) ^ swz) * 16));
      f32x4_t zacc = {};
      zacc = mfma16(aq0, b0, zacc);
      zacc = mfma16(aq1, b1, zacc);
#pragma unroll
      for (int r = 0; r < 4; ++r) sc[cf][r] = zacc[r] * 0.125f;
    }
    __builtin_amdgcn_s_setprio(0);
    if (kv0 + 63 > q0w) {
#pragma unroll
      for (int cf = 0; cf < 4; ++cf)
#pragma unroll
        for (int r = 0; r < 4; ++r) {
          const int qg = q0w + hi * 4 + r;
          const int kg = kv0 + cf * 16 + ln;
          if (kg > qg) sc[cf][r] = -1e30f;
        }
    }
#pragma unroll
    for (int r = 0; r < 4; ++r) {
      float tm = fmaxf(fmaxf(sc[0][r], sc[1][r]), fmaxf(sc[2][r], sc[3][r]));
      tm = fmaxf(tm, __shfl_xor(tm, 1));
      tm = fmaxf(tm, __shfl_xor(tm, 2));
      tm = fmaxf(tm, __shfl_xor(tm, 4));
      tm = fmaxf(tm, __shfl_xor(tm, 8));
      const float mn = fmaxf(m_r[r], tm);
      const float alpha = __expf(m_r[r] - mn);
      float rsum = 0.f;
#pragma unroll
      for (int cf = 0; cf < 4; ++cf) {
        const float p = __expf(sc[cf][r] - mn);
        sc[cf][r] = p; rsum += p;
      }
      rsum += __shfl_xor(rsum, 1); rsum += __shfl_xor(rsum, 2);
      rsum += __shfl_xor(rsum, 4); rsum += __shfl_xor(rsum, 8);
      l_r[r] = l_r[r] * alpha + rsum;
      m_r[r] = mn;
#pragma unroll
      for (int df = 0; df < 4; ++df) o_acc[df][r] *= alpha;
    }
    unsigned short* pw = &pl[wid][0];
#pragma unroll
    for (int cf = 0; cf < 4; ++cf)
#pragma unroll
      for (int r = 0; r < 4; ++r) {
        const int qq = hi * 4 + r;
        const int kv = cf * 16 + ln;
        const int bo = (qq * 128 + kv * 2) ^ ((qq & 7) << 4);
        *(unsigned short*)((char*)pw + bo) = f2bf(sc[cf][r]);
      }
    __syncthreads();  // cross-lane P visibility + kTl/vTl ordering
    const bf16x8_t pa0 = *(const bf16x8_t*)((char*)pw + ((ln * 128 + hi * 16) ^ ((ln & 7) << 4)));
    const bf16x8_t pa1 = *(const bf16x8_t*)((char*)pw + ((ln * 128 + 64 + hi * 16) ^ ((ln & 7) << 4)));
    __builtin_amdgcn_s_setprio(1);
#pragma unroll
    for (int df = 0; df < 4; ++df) {
      const int d = df * 16 + ln;
      const int swz = d & 7;
      const bf16x8_t bv0 = *(const bf16x8_t*)((char*)vTl + d * 128 + ((hi ^ swz) * 16));
      const bf16x8_t bv1 = *(const bf16x8_t*)((char*)vTl + d * 128 + (((4 + hi) ^ swz) * 16));
      o_acc[df] = mfma16(pa0, bv0, o_acc[df]);
      o_acc[df] = mfma16(pa1, bv1, o_acc[df]);
    }
    __builtin_amdgcn_s_setprio(0);
    __syncthreads();
  }
#pragma unroll
  for (int df = 0; df < 4; ++df) {
    const int n = h * 64 + df * 16 + ln;
#pragma unroll
    for (int r = 0; r < 4; ++r) {
      const int m = q0w + hi * 4 + r;
      ao[(size_t)m * 1024 + n] = f2bf(o_acc[df][r] / l_r[r]);
    }
  }
}

// ---------------- gating: recompute LN2 in f32, top-2 of sigmoid, counts ----------------
__global__ __launch_bounds__(256) void gate_kernel(const float* __restrict__ x2, const float* __restrict__ g,
                                                   const float* __restrict__ b, const float* __restrict__ wg,
                                                   int2* __restrict__ te, float2* __restrict__ tw,
                                                   int* __restrict__ cnt) {
  const int tid = threadIdx.x, wid = tid >> 6, lane = tid & 63;
  const int t = blockIdx.x * 4 + wid;
  const float* row = x2 + (size_t)t * 1024;
  float vv[16];
#pragma unroll
  for (int i = 0; i < 4; ++i) *(float4*)&vv[i * 4] = *(const float4*)(row + lane * 16 + i * 4);
  float s = 0.f, s2 = 0.f;
#pragma unroll
  for (int j = 0; j < 16; ++j) { s += vv[j]; s2 += vv[j] * vv[j]; }
#pragma unroll
  for (int o = 1; o < 64; o <<= 1) { s += __shfl_xor(s, o); s2 += __shfl_xor(s2, o); }
  const float mu = s * 0.0009765625f;
  const float var = s2 * 0.0009765625f - mu * mu;
  const float rs = rsqrtf(var + 1e-5f);
  float acc[8] = {0.f, 0.f, 0.f, 0.f, 0.f, 0.f, 0.f, 0.f};
#pragma unroll
  for (int j = 0; j < 16; ++j) {
    const int d = lane * 16 + j;
    const float xv = (vv[j] - mu) * rs * g[d] + b[d];
    const float4 w0 = *(const float4*)(wg + d * 8);
    const float4 w1 = *(const float4*)(wg + d * 8 + 4);
    acc[0] += xv * w0.x; acc[1] += xv * w0.y; acc[2] += xv * w0.z; acc[3] += xv * w0.w;
    acc[4] += xv * w1.x; acc[5] += xv * w1.y; acc[6] += xv * w1.z; acc[7] += xv * w1.w;
  }
#pragma unroll
  for (int o = 1; o < 64; o <<= 1) {
#pragma unroll
    for (int e = 0; e < 8; ++e) acc[e] += __shfl_xor(acc[e], o);
  }
  if (lane == 0) {
    float sg[8];
#pragma unroll
    for (int e = 0; e < 8; ++e) sg[e] = 1.f / (1.f + __expf(-acc[e]));
    int e0 = 0;
#pragma unroll
    for (int e = 1; e < 8; ++e) if (sg[e] > sg[e0]) e0 = e;
    int e1 = (e0 == 0) ? 1 : 0;
#pragma unroll
    for (int e = 0; e < 8; ++e) if (e != e0 && sg[e] > sg[e1]) e1 = e;
    const float v0 = sg[e0], v1 = sg[e1];
    const float inv = 1.f / (v0 + v1 + 1e-9f);
    te[t] = make_int2(e0, e1);
    tw[t] = make_float2(v0 * inv, v1 * inv);
    atomicAdd(&cnt[e0], 1);
    atomicAdd(&cnt[e1], 1);
  }
}

__global__ void zero_counters(int* p) { if (threadIdx.x < 8) p[threadIdx.x] = 0; }

// ---------------- routing phase 2: 256-row tiles, padded offsets + metadata ----------------
__global__ __launch_bounds__(256) void g2_kernel(const int* __restrict__ cnt, int* __restrict__ slot_off,
                                                 int* __restrict__ tile_expert, int* __restrict__ tile_rowbase,
                                                 int* __restrict__ cursor, int* __restrict__ assign_token,
                                                 float* __restrict__ assign_w) {
  const int tid = threadIdx.x;
  for (int i = tid; i < 8192; i += 256) { assign_token[i] = -1; assign_w[i] = 0.f; }
  if (tid == 0) {
    int base = 0, tiles = 0;
    for (int e = 0; e < 8; ++e) {
      const int c = cnt[e];
      slot_off[e] = base;
      cursor[e] = 0;
      const int nt = (c + 255) >> 8;
      for (int i = 0; i < nt; ++i) {
        tile_expert[tiles] = e;
        tile_rowbase[tiles] = base + i * 256;
        ++tiles;
      }
      base += nt * 256;
    }
    for (; tiles < 40; ++tiles) tile_expert[tiles] = -1;
  }
}

// ---------------- routing phase 3: scatter assignments ----------------
__global__ __launch_bounds__(256) void g3_kernel(const int2* __restrict__ te, const float2* __restrict__ tw,
                                                 const int* __restrict__ slot_off, int* __restrict__ cursor,
                                                 int* __restrict__ assign_token, float* __restrict__ assign_w) {
  const int t = blockIdx.x * 256 + threadIdx.x;
  const int2 e = te[t];
  const float2 w = tw[t];
  const int s0 = slot_off[e.x] + atomicAdd(&cursor[e.x], 1);
  assign_token[s0] = t; assign_w[s0] = w.x;
  const int s1 = slot_off[e.y] + atomicAdd(&cursor[e.y], 1);
  assign_token[s1] = t; assign_w[s1] = w.y;
}

// ---- stage a 256x32 A tile (16KB) = 4 gload16 ----
DI void stageA4(const unsigned short* a0, const unsigned short* a1,
                const unsigned short* a2, const unsigned short* a3,
                int koff, char* Ab, int wid) {
  gload16(a0 + koff, Ab + wid * 1024);
  gload16(a1 + koff, Ab + 4096 + wid * 1024);
  gload16(a2 + koff, Ab + 8192 + wid * 1024);
  gload16(a3 + koff, Ab + 12288 + wid * 1024);
}
// ---- stage a 128x32 A tile (8KB) = 2 gload16 ----
DI void stageA2(const unsigned short* a0, const unsigned short* a1,
                int koff, char* Ab, int wid) {
  gload16(a0 + koff, Ab + wid * 1024);
  gload16(a1 + koff, Ab + 4096 + wid * 1024);
}

// ---- upgate helpers (BM=256) ----
DI void ug_write_b(char* Bn, const int* boff, const float4& q0, const float4& q1,
                   const float4& q2, const float4& q3) {
  const float* q0p = (const float*)&q0; const float* q1p = (const float*)&q1;
  const float* q2p = (const float*)&q2; const float* q3p = (const float*)&q3;
#pragma unroll
  for (int i = 0; i < 4; ++i) {
    uint2 w;
    w.x = pk2(q0p[i], q1p[i]);
    w.y = pk2(q2p[i], q3p[i]);
    *(uint2*)(Bn + boff[i]) = w;
  }
}

DI void ug_mfma256(const unsigned short* A, const char* Bb, int wr, int wc, int ln, int hi,
                   f32x4_t (&accg)[8][2], f32x4_t (&accu)[8][2]) {
  bf16x8_t af[8];
#pragma unroll
  for (int mf = 0; mf < 8; ++mf)
    af[mf] = frag(A, wr * 128 + mf * 16 + ln, hi);
  __builtin_amdgcn_s_setprio(1);
#pragma unroll
  for (int nf = 0; nf < 2; ++nf) {
    const int nrow = wc * 32 + nf * 16 + ln;
    int bo = nrow * 64 + hi * 16;
    bo ^= ((nrow >> 2) & 7) << 4;
    const bf16x8_t bg = *(const bf16x8_t*)(Bb + bo);
    const bf16x8_t bu = *(const bf16x8_t*)(Bb + 4096 + bo);
#pragma unroll
    for (int mf = 0; mf < 8; ++mf) {
      accg[mf][nf] = mfma16(af[mf], bg, accg[mf][nf]);
      accu[mf][nf] = mfma16(af[mf], bu, accu[mf][nf]);
    }
  }
  __builtin_amdgcn_s_setprio(0);
}

// ---------------- MoE up+gate: BM=256, A-first issue order (race-free 2-deep B) ----------
__global__ __launch_bounds__(256, 2) void upgate_kernel(const unsigned short* __restrict__ h2,
                                                        const float* __restrict__ w_eg, const float* __restrict__ w_eu,
                                                        const int* __restrict__ tile_expert,
                                                        const int* __restrict__ tile_rowbase,
                                                        const int* __restrict__ assign_token,
                                                        unsigned short* __restrict__ act) {
  const int by = blockIdx.y;
  const int e = tile_expert[by];
  if (e < 0) return;
  const int n0 = blockIdx.x * 64;
  const int rowbase = tile_rowbase[by];
  const int tid = threadIdx.x;
  __shared__ unsigned short lds[2 * 8192 + 2 * 4096];  // A dbuf 2x16KB, B dbuf 2x8KB
  char* A0 = (char*)lds;
  char* A1 = (char*)lds + 16384;
  char* B0 = (char*)lds + 32768;
  char* B1 = (char*)lds + 40960;
  const int wid = tid >> 6, lane = tid & 63, ln = lane & 15, hi = lane >> 4;
  const int wr = wid >> 1, wc = wid & 1;
  const int r0s = rowbase + (tid >> 2);
  int tk0 = assign_token[r0s];        tk0 = tk0 < 0 ? 0 : tk0;
  int tk1 = assign_token[r0s + 64];   tk1 = tk1 < 0 ? 0 : tk1;
  int tk2 = assign_token[r0s + 128];  tk2 = tk2 < 0 ? 0 : tk2;
  int tk3 = assign_token[r0s + 192];  tk3 = tk3 < 0 ? 0 : tk3;
  const int cs = chunk_swz(tid);
  const unsigned short* aR0 = h2 + (size_t)tk0 * 1024 + cs;
  const unsigned short* aR1 = h2 + (size_t)tk1 * 1024 + cs;
  const unsigned short* aR2 = h2 + (size_t)tk2 * 1024 + cs;
  const unsigned short* aR3 = h2 + (size_t)tk3 * 1024 + cs;
  const int mat = tid >> 7;
  const int blk = tid & 127;
  const int kb = (blk >> 4) * 4;
  const int nb = (blk & 15) * 4;
  const float* bsrc = (mat ? w_eu : w_eg) + (size_t)e * 1024 * 4096 + (size_t)kb * 4096 + n0 + nb;
  int boff[4];
#pragma unroll
  for (int i = 0; i < 4; ++i) {
    const int n = nb + i;
    int bo = mat * 4096 + n * 64 + kb * 2;
    bo ^= ((n >> 2) & 7) << 4;
    boff[i] = bo;
  }
  f32x4_t accg[8][2] = {};
  f32x4_t accu[8][2] = {};
  float4 qA0, qA1, qA2, qA3, qB0, qB1, qB2, qB3;
  // ---- prologue: A(0)->A0; B(0)->regs; write B0 (drains A(0) too, FIFO); B(1)->qA ----
  stageA4(aR0, aR1, aR2, aR3, 0, A0, wid);
  qB0 = *(const float4*)(bsrc);
  qB1 = *(const float4*)(bsrc + 4096);
  qB2 = *(const float4*)(bsrc + 8192);
  qB3 = *(const float4*)(bsrc + 12288);
  __builtin_amdgcn_sched_barrier(0);
  ug_write_b(B0, boff, qB0, qB1, qB2, qB3);
  {
    const float* bs = bsrc + (size_t)32 * 4096;
    qA0 = *(const float4*)(bs);
    qA1 = *(const float4*)(bs + 4096);
    qA2 = *(const float4*)(bs + 8192);
    qA3 = *(const float4*)(bs + 12288);
  }
  asm volatile("s_waitcnt lgkmcnt(0)" ::: "memory");
  __builtin_amdgcn_sched_barrier(0);
  __builtin_amdgcn_s_barrier();
  // ---- main: t = 0..29 (15 pairs) ----
  for (int p = 0; p < 15; ++p) {
    {  // even t=2p: compute A0/B0; stage A(t+1)->A1; load B(t+2)->qB
      const int t = 2 * p;
      stageA4(aR0, aR1, aR2, aR3, (t + 1) * 32, A1, wid);
      const float* bs = bsrc + (size_t)(t + 2) * 32 * 4096;
      qB0 = *(const float4*)(bs);
      qB1 = *(const float4*)(bs + 4096);
      qB2 = *(const float4*)(bs + 8192);
      qB3 = *(const float4*)(bs + 12288);
      __builtin_amdgcn_sched_barrier(0);
      ug_write_b(B1, boff, qA0, qA1, qA2, qA3);   // implied vmcnt(8): keeps A(t+1)+B(t+2)
      ug_mfma256((const unsigned short*)A0, B0, wr, wc, ln, hi, accg, accu);
      asm volatile("s_waitcnt vmcnt(4)" ::: "memory");  // retire A(t+1)x4; keep B(t+2)x4
      __builtin_amdgcn_sched_barrier(0);
      asm volatile("s_waitcnt lgkmcnt(0)" ::: "memory");
      __builtin_amdgcn_sched_barrier(0);
      __builtin_amdgcn_s_barrier();
    }
    {  // odd t=2p+1: compute A1/B1
      const int t = 2 * p + 1;
      stageA4(aR0, aR1, aR2, aR3, (t + 1) * 32, A0, wid);
      const float* bs = bsrc + (size_t)(t + 2) * 32 * 4096;
      qA0 = *(const float4*)(bs);
      qA1 = *(const float4*)(bs + 4096);
      qA2 = *(const float4*)(bs + 8192);
      qA3 = *(const float4*)(bs + 12288);
      __builtin_amdgcn_sched_barrier(0);
      ug_write_b(B0, boff, qB0, qB1, qB2, qB3);
      ug_mfma256((const unsigned short*)A1, B1, wr, wc, ln, hi, accg, accu);
      asm volatile("s_waitcnt vmcnt(4)" ::: "memory");
      __builtin_amdgcn_sched_barrier(0);
      asm volatile("s_waitcnt lgkmcnt(0)" ::: "memory");
      __builtin_amdgcn_sched_barrier(0);
      __builtin_amdgcn_s_barrier();
    }
  }
  // ---- t=30 (A0/B0): stage A(31)->A1; write B(31) from qA; drain all ----
  stageA4(aR0, aR1, aR2, aR3, 31 * 32, A1, wid);
  __builtin_amdgcn_sched_barrier(0);
  ug_write_b(B1, boff, qA0, qA1, qA2, qA3);   // implied vmcnt(4): keeps A(31)
  ug_mfma256((const unsigned short*)A0, B0, wr, wc, ln, hi, accg, accu);
  asm volatile("s_waitcnt vmcnt(0)" ::: "memory");
  __builtin_amdgcn_sched_barrier(0);
  asm volatile("s_waitcnt lgkmcnt(0)" ::: "memory");
  __builtin_amdgcn_sched_barrier(0);
  __builtin_amdgcn_s_barrier();
  // ---- t=31: MFMA only ----
  ug_mfma256((const unsigned short*)A1, B1, wr, wc, ln, hi, accg, accu);
#pragma unroll
  for (int mf = 0; mf < 8; ++mf)
#pragma unroll
    for (int nf = 0; nf < 2; ++nf)
#pragma unroll
      for (int r = 0; r < 4; ++r) {
        const int m = wr * 128 + mf * 16 + hi * 4 + r;
        const int n = n0 + wc * 32 + nf * 16 + ln;
        const float gv = accg[mf][nf][r], uv = accu[mf][nf][r];
        const float val = gv / (1.f + __expf(-gv)) * uv;
        act[(size_t)(rowbase + m) * 4096 + n] = f2bf(val);
      }
}

// ---- down helpers (BM=128) ----
DI void dn_write_b(char* Bn, const int* boff, const float4& q0, const float4& q1) {
  const float* q0p = (const float*)&q0; const float* q1p = (const float*)&q1;
#pragma unroll
  for (int i = 0; i < 4; ++i)
    *(uint32_t*)(Bn + boff[i]) = pk2(q0p[i], q1p[i]);
}

DI void dn_mfma(const unsigned short* A, const char* Bb, int wr, int wc, int ln, int hi,
                f32x4_t (&acc)[4][2]) {
  bf16x8_t af[4];
#pragma unroll
  for (int mf = 0; mf < 4; ++mf)
    af[mf] = frag(A, wr * 64 + mf * 16 + ln, hi);
  __builtin_amdgcn_s_setprio(1);
#pragma unroll
  for (int nf = 0; nf < 2; ++nf) {
    const int nrow = wc * 32 + nf * 16 + ln;
    int bo = nrow * 64 + hi * 16;
    bo ^= ((nrow >> 2) & 7) << 4;
    const bf16x8_t bb = *(const bf16x8_t*)(Bb + bo);
#pragma unroll
    for (int mf = 0; mf < 4; ++mf)
      acc[mf][nf] = mfma16(af[mf], bb, acc[mf][nf]);
  }
  __builtin_amdgcn_s_setprio(0);
}

// ---------------- MoE down: BM=128, split-K x4 (free via atomicAdd), A-first order --------
// grid (16 n0, 48 half-tiles, 4 kz); each block: K-slice of 1024 (32 steps).
__global__ __launch_bounds__(256) void down_kernel(const unsigned short* __restrict__ act,
                                                   const float* __restrict__ w_ed,
                                                   const int* __restrict__ tile_expert,
                                                   const int* __restrict__ tile_rowbase,
                                                   const int* __restrict__ assign_token,
                                                   const float* __restrict__ assign_w,
                                                   float* __restrict__ out) {
  const int tix = blockIdx.y;
  const int e = tile_expert[tix >> 1];
  if (e < 0) return;
  const int rowbase = tile_rowbase[tix >> 1] + (tix & 1) * 128;
  const int n0 = blockIdx.x * 64;
  const int kz = blockIdx.z * 1024;
  const int tid = threadIdx.x;
  __shared__ unsigned short lds[2 * 4096 + 2 * 2048];  // A dbuf 2x8KB, B dbuf 2x4KB
  char* A0 = (char*)lds;
  char* A1 = (char*)lds + 8192;
  char* B0 = (char*)lds + 16384;
  char* B1 = (char*)lds + 20480;
  const int wid = tid >> 6, lane = tid & 63, ln = lane & 15, hi = lane >> 4;
  const int wr = wid >> 1, wc = wid & 1;
  const int cs = chunk_swz(tid);
  const unsigned short* aR0 = act + (size_t)(rowbase + (tid >> 2)) * 4096 + kz + cs;
  const unsigned short* aR1 = aR0 + (size_t)64 * 4096;
  const int nb = (tid & 15) * 4;
  const int kb2 = (tid >> 4) * 2;
  const float* bsrc = w_ed + (size_t)e * 4096 * 1024 + (size_t)(kz + kb2) * 1024 + n0 + nb;
  int boff[4];
#pragma unroll
  for (int i = 0; i < 4; ++i) {
    const int n = nb + i;
    int bo = n * 64 + kb2 * 2;
    bo ^= ((n >> 2) & 7) << 4;
    boff[i] = bo;
  }
  f32x4_t acc[4][2] = {};
  float4 qA0, qA1, qB0, qB1;
  // ---- prologue ----
  stageA2(aR0, aR1, 0, A0, wid);
  qB0 = *(const float4*)(bsrc);
  qB1 = *(const float4*)(bsrc + 1024);
  __builtin_amdgcn_sched_barrier(0);
  dn_write_b(B0, boff, qB0, qB1);   // implied wait drains A(0) too (older in FIFO)
  {
    const float* bs = bsrc + (size_t)32 * 1024;
    qA0 = *(const float4*)(bs);
    qA1 = *(const float4*)(bs + 1024);
  }
  asm volatile("s_waitcnt lgkmcnt(0)" ::: "memory");
  __builtin_amdgcn_sched_barrier(0);
  __builtin_amdgcn_s_barrier();
  // ---- main: t = 0..29 (15 pairs) ----
  for (int p = 0; p < 15; ++p) {
    {  // even t=2p
      const int t = 2 * p;
      stageA2(aR0, aR1, (t + 1) * 32, A1, wid);
      const float* bs = bsrc + (size_t)(t + 2) * 32 * 1024;
      qB0 = *(const float4*)(bs);
      qB1 = *(const float4*)(bs + 1024);
      __builtin_amdgcn_sched_barrier(0);
      dn_write_b(B1, boff, qA0, qA1);   // implied vmcnt(4): keeps A(t+1)x2 + B(t+2)x2
      dn_mfma((const unsigned short*)A0, B0, wr, wc, ln, hi, acc);
      asm volatile("s_waitcnt vmcnt(2)" ::: "memory");  // retire A(t+1); keep B(t+2)
      __builtin_amdgcn_sched_barrier(0);
      asm volatile("s_waitcnt lgkmcnt(0)" ::: "memory");
      __builtin_amdgcn_sched_barrier(0);
      __builtin_amdgcn_s_barrier();
    }
    {  // odd t=2p+1
      const int t = 2 * p + 1;
      stageA2(aR0, aR1, (t + 1) * 32, A0, wid);
      const float* bs = bsrc + (size_t)(t + 2) * 32 * 1024;
      qA0 = *(const float4*)(bs);
      qA1 = *(const float4*)(bs + 1024);
      __builtin_amdgcn_sched_barrier(0);
      dn_write_b(B0, boff, qB0, qB1);
      dn_mfma((const unsigned short*)A1, B1, wr, wc, ln, hi, acc);
      asm volatile("s_waitcnt vmcnt(2)" ::: "memory");
      __builtin_amdgcn_sched_barrier(0);
      asm volatile("s_waitcnt lgkmcnt(0)" ::: "memory");
      __builtin_amdgcn_sched_barrier(0);
      __builtin_amdgcn_s_barrier();
    }
  }
  // ---- t=30: stage A(31); write B(31) from qA; drain ----
  stageA2(aR0, aR1, 31 * 32, A1, wid);
  __builtin_amdgcn_sched_barrier(0);
  dn_write_b(B1, boff, qA0, qA1);
  dn_mfma((const unsigned short*)A0, B0, wr, wc, ln, hi, acc);
  asm volatile("s_waitcnt vmcnt(0)" ::: "memory");
  __builtin_amdgcn_sched_barrier(0);
  asm volatile("s_waitcnt lgkmcnt(0)" ::: "memory");
  __builtin_amdgcn_sched_barrier(0);
  __builtin_amdgcn_s_barrier();
  // ---- t=31 ----
  dn_mfma((const unsigned short*)A1, B1, wr, wc, ln, hi, acc);
#pragma unroll
  for (int mf = 0; mf < 4; ++mf)
#pragma unroll
    for (int r = 0; r < 4; ++r) {
      const int m = wr * 64 + mf * 16 + hi * 4 + r;
      const int slot = rowbase + m;
      const int tk = assign_token[slot];
      if (tk >= 0) {
        const float w = assign_w[slot];
#pragma unroll
        for (int nf = 0; nf < 2; ++nf) {
          const int n = n0 + wc * 32 + nf * 16 + ln;
          atomicAdd(out + (size_t)tk * 1024 + n, acc[mf][nf][r] * w);
        }
      }
    }
}

// ---------------- host launcher ----------------
extern "C" void kernel_launch(void* const* d_in, const int* in_sizes, int n_in,
                              void* d_out, int out_size, void* d_ws, size_t ws_size,
                              hipStream_t stream) {
  (void)in_sizes; (void)n_in; (void)out_size;
  const float* x    = (const float*)d_in[0];
  const float* ln1g = (const float*)d_in[1];
  const float* ln1b = (const float*)d_in[2];
  const float* wq   = (const float*)d_in[3];
  const float* wk   = (const float*)d_in[4];
  const float* wv   = (const float*)d_in[5];
  const float* wo   = (const float*)d_in[6];
  const float* ln2g = (const float*)d_in[7];
  const float* ln2b = (const float*)d_in[8];
  const float* wg   = (const float*)d_in[9];
  const float* weg  = (const float*)d_in[10];
  const float* weu  = (const float*)d_in[11];
  const float* wed  = (const float*)d_in[12];
  float* out = (float*)d_out;
  char* ws = (char*)d_ws;

  const size_t MB = (size_t)1 << 20;
  if (ws_size < 86 * MB) return;
  unsigned short* wqT = (unsigned short*)(ws + 0 * MB);
  unsigned short* wkT = (unsigned short*)(ws + 2 * MB);
  unsigned short* wvT = (unsigned short*)(ws + 4 * MB);
  unsigned short* woT = (unsigned short*)(ws + 6 * MB);
  unsigned short* h1  = (unsigned short*)(ws + 8 * MB);
  unsigned short* qb  = (unsigned short*)(ws + 12 * MB);
  unsigned short* kbf = (unsigned short*)(ws + 16 * MB);
  unsigned short* vt  = (unsigned short*)(ws + 20 * MB);
  unsigned short* ao  = (unsigned short*)(ws + 24 * MB);
  unsigned short* h2  = (unsigned short*)(ws + 28 * MB);
  unsigned short* act = (unsigned short*)(ws + 32 * MB);  // 6144*4096*2 = 48MiB (52MB slot)
  int2*   te = (int2*)(ws + 84 * MB);
  float2* tw = (float2*)(ws + 84 * MB + 16384);
  int*  meta = (int*)(ws + 84 * MB + 32768);
  int* cnt = meta;
  int* cursor = meta + 8;
  int* slot_off = meta + 16;
  int* tile_expert = meta + 24;
  int* tile_rowbase = meta + 64;
  int*   assign_token = (int*)(ws + 84 * MB + 36864);
  float* assign_w     = (float*)(ws + 84 * MB + 36864 + 32768);

  zero_counters<<<1, 64, 0, stream>>>(cnt);
  transpose_cvt4<<<dim3(16, 16, 4), 256, 0, stream>>>(wq, wk, wv, wo, wqT, wkT, wvT, woT);
  ln_kernel<<<2048, 256, 0, stream>>>(x, ln1g, ln1b, h1);
  qkv_kernel<<<dim3(8, 16, 3), 256, 0, stream>>>(h1, wqT, wkT, wvT, qb, kbf, vt);
  attn_kernel<<<dim3(32, 16), 256, 0, stream>>>(qb, kbf, vt, ao);
  wo_kernel<<<dim3(16, 16), 256, 0, stream>>>(ao, woT, x, out);
  ln_kernel<<<2048, 256, 0, stream>>>(out, ln2g, ln2b, h2);
  gate_kernel<<<512, 256, 0, stream>>>(out, ln2g, ln2b, wg, te, tw, cnt);
  g2_kernel<<<1, 256, 0, stream>>>(cnt, slot_off, tile_expert, tile_rowbase, cursor, assign_token, assign_w);
  g3_kernel<<<8, 256, 0, stream>>>(te, tw, slot_off, cursor, assign_token, assign_w);
  upgate_kernel<<<dim3(64, 24), 256, 0, stream>>>(h2, weg, weu, tile_expert, tile_rowbase, assign_token, act);
  down_kernel<<<dim3(16, 48, 4), 256, 0, stream>>>(act, wed, tile_expert, tile_rowbase, assign_token, assign_w, out);
}

// Round 15
// 481.189 us; speedup vs baseline: 1.0536x; 1.0116x over previous
//
#include <hip/hip_runtime.h>
#include <hip/hip_bf16.h>
#include <stdint.h>

#define DI __device__ __forceinline__

typedef short bf16x8_t __attribute__((ext_vector_type(8)));
typedef float f32x4_t __attribute__((ext_vector_type(4)));

DI unsigned short f2bf(float f) {
  __hip_bfloat16 h = __float2bfloat16(f);
  unsigned short u;
  __builtin_memcpy(&u, &h, 2);
  return u;
}

// pair f32 -> packed 2xbf16 (compiler emits v_cvt_pk_bf16_f32)
DI uint32_t pk2(float a, float b) {
  return (uint32_t)f2bf(a) | ((uint32_t)f2bf(b) << 16);
}

DI f32x4_t mfma16(bf16x8_t a, bf16x8_t b, f32x4_t c) {
  return __builtin_amdgcn_mfma_f32_16x16x32_bf16(a, b, c, 0, 0, 0);
}

DI void gload16(const void* g, void* l) {
  __builtin_amdgcn_global_load_lds(
      (const __attribute__((address_space(1))) uint32_t*)g,
      (__attribute__((address_space(3))) uint32_t*)l, 16, 0, 0);
}

// A/B tile fragment read with chunk swizzle matching pre-swizzled global source:
// lds[row][chunk ^ ((row>>1)&3)], tile row = 32 shorts (64B), chunk = 8 shorts (16B)
DI bf16x8_t frag(const unsigned short* base, int row, int hi) {
  return *(const bf16x8_t*)&base[row * 32 + ((hi ^ ((row >> 1) & 3)) * 8)];
}
// per-lane source chunk offset (in shorts) for gload16 A/B staging
DI int chunk_swz(int tid) { return ((tid & 3) ^ ((tid >> 3) & 3)) * 8; }

// ---------------- fused transpose + f32->bf16 for 4 square matrices (z selects) ----------
__global__ __launch_bounds__(256) void transpose_cvt4(const float* __restrict__ s0, const float* __restrict__ s1,
                                                      const float* __restrict__ s2, const float* __restrict__ s3,
                                                      unsigned short* __restrict__ d0, unsigned short* __restrict__ d1,
                                                      unsigned short* __restrict__ d2, unsigned short* __restrict__ d3) {
  __shared__ float tile[64][65];
  const int z = blockIdx.z;
  const float* in = (z == 0) ? s0 : (z == 1) ? s1 : (z == 2) ? s2 : s3;
  unsigned short* out = (z == 0) ? d0 : (z == 1) ? d1 : (z == 2) ? d2 : d3;
  const int tid = threadIdx.x;
  const int tx = tid & 15, ty = tid >> 4;
  const int r0 = blockIdx.y * 64, c0 = blockIdx.x * 64;
#pragma unroll
  for (int i = 0; i < 4; ++i) {
    const int r = ty + i * 16;
    const float4 v = *(const float4*)(in + (size_t)(r0 + r) * 1024 + c0 + tx * 4);
    tile[r][tx * 4 + 0] = v.x; tile[r][tx * 4 + 1] = v.y;
    tile[r][tx * 4 + 2] = v.z; tile[r][tx * 4 + 3] = v.w;
  }
  __syncthreads();
#pragma unroll
  for (int i = 0; i < 4; ++i) {
    const int r = ty + i * 16;
    ushort4 o;
    o.x = f2bf(tile[tx * 4 + 0][r]); o.y = f2bf(tile[tx * 4 + 1][r]);
    o.z = f2bf(tile[tx * 4 + 2][r]); o.w = f2bf(tile[tx * 4 + 3][r]);
    *(ushort4*)(out + (size_t)(c0 + r) * 1024 + r0 + tx * 4) = o;
  }
}

// ---------------- LayerNorm f32 -> bf16 (used for LN1 only) ----------------
__global__ __launch_bounds__(256) void ln_kernel(const float* __restrict__ x, const float* __restrict__ g,
                                                 const float* __restrict__ b, unsigned short* __restrict__ out) {
  const int row = blockIdx.x, tid = threadIdx.x;
  const int wid = tid >> 6, lane = tid & 63;
  const float4 v = *(const float4*)(x + (size_t)row * 1024 + tid * 4);
  float s = v.x + v.y + v.z + v.w;
  float s2 = v.x * v.x + v.y * v.y + v.z * v.z + v.w * v.w;
#pragma unroll
  for (int o = 1; o < 64; o <<= 1) { s += __shfl_xor(s, o); s2 += __shfl_xor(s2, o); }
  __shared__ float red[8];
  if (lane == 0) { red[wid] = s; red[4 + wid] = s2; }
  __syncthreads();
  const float ts = red[0] + red[1] + red[2] + red[3];
  const float ts2 = red[4] + red[5] + red[6] + red[7];
  const float mu = ts * 0.0009765625f;
  const float var = ts2 * 0.0009765625f - mu * mu;
  const float rs = rsqrtf(var + 1e-5f);
  const float4 gg = *(const float4*)(g + tid * 4);
  const float4 bb = *(const float4*)(b + tid * 4);
  ushort4 o4;
  o4.x = f2bf((v.x - mu) * rs * gg.x + bb.x);
  o4.y = f2bf((v.y - mu) * rs * gg.y + bb.y);
  o4.z = f2bf((v.z - mu) * rs * gg.z + bb.z);
  o4.w = f2bf((v.w - mu) * rs * gg.w + bb.w);
  *(ushort4*)(out + (size_t)row * 1024 + tid * 4) = o4;
}

// ---------------- generic bf16 GEMM core: BM=128, BK=32, 256 thr, waves 2x2 ----------------
template<int BN>
DI void gemm_loop(const unsigned short* aR0, const unsigned short* aR1,
                  const unsigned short* bR0, const unsigned short* bR1,
                  const int K, unsigned short* lds, const int tid,
                  f32x4_t (&acc)[4][BN / 32]) {
  constexpr int NF = BN / 32;
  unsigned short* ldsA = lds;
  unsigned short* ldsB = lds + 4096;  // 128*32
  const int wid = tid >> 6, lane = tid & 63, ln = lane & 15, hi = lane >> 4;
  const int wr = wid >> 1, wc = wid & 1;
  char* dstA0 = (char*)ldsA + wid * 1024;
  char* dstA1 = (char*)ldsA + 4096 + wid * 1024;
  char* dstB0 = (char*)ldsB + wid * 1024;
  char* dstB1 = (char*)ldsB + 4096 + wid * 1024;
  for (int k0 = 0; k0 < K; k0 += 32) {
    gload16(aR0 + k0, dstA0);
    gload16(aR1 + k0, dstA1);
    gload16(bR0 + k0, dstB0);
    if constexpr (BN == 128) gload16(bR1 + k0, dstB1);
    __syncthreads();
    bf16x8_t af[4];
#pragma unroll
    for (int mf = 0; mf < 4; ++mf)
      af[mf] = frag(ldsA, wr * 64 + mf * 16 + ln, hi);
    __builtin_amdgcn_s_setprio(1);
#pragma unroll
    for (int nf = 0; nf < NF; ++nf) {
      bf16x8_t bfr = frag(ldsB, wc * (BN / 2) + nf * 16 + ln, hi);
#pragma unroll
      for (int mf = 0; mf < 4; ++mf)
        acc[mf][nf] = mfma16(af[mf], bfr, acc[mf][nf]);
    }
    __builtin_amdgcn_s_setprio(0);
    __syncthreads();
  }
}

// ---------------- QKV projections (z = 0:Q, 1:K, 2:V-transposed) ----------------
__global__ __launch_bounds__(256) void qkv_kernel(const unsigned short* __restrict__ h1,
                                                  const unsigned short* __restrict__ wqT,
                                                  const unsigned short* __restrict__ wkT,
                                                  const unsigned short* __restrict__ wvT,
                                                  unsigned short* __restrict__ qb,
                                                  unsigned short* __restrict__ kbf,
                                                  unsigned short* __restrict__ vt) {
  __shared__ unsigned short lds[128 * 32 + 128 * 32];
  const int tid = threadIdx.x;
  const int z = blockIdx.z;
  const unsigned short* BT = (z == 0) ? wqT : (z == 1) ? wkT : wvT;
  const int m0 = blockIdx.y * 128, n0 = blockIdx.x * 128;
  f32x4_t acc[4][4] = {};
  const int cs = chunk_swz(tid);
  const unsigned short* aR0 = h1 + (size_t)(m0 + (tid >> 2)) * 1024 + cs;
  const unsigned short* aR1 = aR0 + 64 * 1024;
  const unsigned short* bR0 = BT + (size_t)(n0 + (tid >> 2)) * 1024 + cs;
  const unsigned short* bR1 = bR0 + 64 * 1024;
  gemm_loop<128>(aR0, aR1, bR0, bR1, 1024, lds, tid, acc);
  const int lane = tid & 63, ln = lane & 15, hi = lane >> 4, wid = tid >> 6;
  const int wr = wid >> 1, wc = wid & 1;
  if (z < 2) {
    unsigned short* o = z ? kbf : qb;
#pragma unroll
    for (int mf = 0; mf < 4; ++mf)
#pragma unroll
      for (int nf = 0; nf < 4; ++nf)
#pragma unroll
        for (int r = 0; r < 4; ++r) {
          const int m = m0 + wr * 64 + mf * 16 + hi * 4 + r;
          const int n = n0 + wc * 64 + nf * 16 + ln;
          o[(size_t)m * 1024 + n] = f2bf(acc[mf][nf][r]);
        }
  } else {
#pragma unroll
    for (int mf = 0; mf < 4; ++mf)
#pragma unroll
      for (int nf = 0; nf < 4; ++nf) {
        const int n = n0 + wc * 64 + nf * 16 + ln;
        const int mb = m0 + wr * 64 + mf * 16 + hi * 4;
        ushort4 o;
        o.x = f2bf(acc[mf][nf][0]); o.y = f2bf(acc[mf][nf][1]);
        o.z = f2bf(acc[mf][nf][2]); o.w = f2bf(acc[mf][nf][3]);
        *(ushort4*)(vt + (size_t)n * 2048 + mb) = o;
      }
  }
}

// ---------------- output projection + residual -> f32 d_out ----------------
__global__ __launch_bounds__(256) void wo_kernel(const unsigned short* __restrict__ ao,
                                                 const unsigned short* __restrict__ woT,
                                                 const float* __restrict__ x,
                                                 float* __restrict__ out) {
  __shared__ unsigned short lds[128 * 32 + 64 * 32];
  const int tid = threadIdx.x;
  const int m0 = blockIdx.y * 128, n0 = blockIdx.x * 64;
  f32x4_t acc[4][2] = {};
  const int cs = chunk_swz(tid);
  const unsigned short* aR0 = ao + (size_t)(m0 + (tid >> 2)) * 1024 + cs;
  const unsigned short* aR1 = aR0 + 64 * 1024;
  const unsigned short* bR0 = woT + (size_t)(n0 + (tid >> 2)) * 1024 + cs;
  gemm_loop<64>(aR0, aR1, bR0, nullptr, 1024, lds, tid, acc);
  const int lane = tid & 63, ln = lane & 15, hi = lane >> 4, wid = tid >> 6;
  const int wr = wid >> 1, wc = wid & 1;
#pragma unroll
  for (int mf = 0; mf < 4; ++mf)
#pragma unroll
    for (int nf = 0; nf < 2; ++nf)
#pragma unroll
      for (int r = 0; r < 4; ++r) {
        const int m = m0 + wr * 64 + mf * 16 + hi * 4 + r;
        const int n = n0 + wc * 32 + nf * 16 + ln;
        out[(size_t)m * 1024 + n] = acc[mf][nf][r] + x[(size_t)m * 1024 + n];
      }
}

// ---------------- flash attention, causal, head_dim 64 ----------------
// Load-balance: co-resident pair (x,h)/(x,h+8) -> complementary q-tiles (qi / 31-qi):
// each CU's two blocks sum to a constant 33 KV-iterations.
// Mid-loop P round-trip is WAVE-LOCAL (pl[wid]) -> lgkmcnt(0) suffices, no block barrier.
__global__ __launch_bounds__(256) void attn_kernel(const unsigned short* __restrict__ qb,
                                                   const unsigned short* __restrict__ kbuf,
                                                   const unsigned short* __restrict__ vt,
                                                   unsigned short* __restrict__ ao) {
  __shared__ unsigned short kTl[4096];
  __shared__ unsigned short vTl[4096];
  __shared__ unsigned short pl[4][1024];
  const int tid = threadIdx.x;
  const int wid = tid >> 6, lane = tid & 63;
  const int ln = lane & 15, hi = lane >> 4;
  const int h = blockIdx.y;
  const int qi = (h < 8) ? blockIdx.x : (31 - blockIdx.x);
  const int q0 = qi * 64;
  const int q0w = q0 + wid * 16;

  const unsigned short* qrow = qb + (size_t)(q0w + ln) * 1024 + h * 64 + hi * 8;
  const bf16x8_t aq0 = *(const bf16x8_t*)(qrow);
  const bf16x8_t aq1 = *(const bf16x8_t*)(qrow + 32);

  const int str_r = tid >> 3, str_c = tid & 7;
  const int swc = (str_c ^ (str_r & 7)) * 8;
  const unsigned short* ksrc0 = kbuf + (size_t)str_r * 1024 + h * 64 + swc;
  const unsigned short* ksrc1 = kbuf + (size_t)(str_r + 32) * 1024 + h * 64 + swc;
  const unsigned short* vsrc0 = vt + (size_t)(h * 64 + str_r) * 2048 + swc;
  const unsigned short* vsrc1 = vt + (size_t)(h * 64 + str_r + 32) * 2048 + swc;
  char* kd0 = (char*)kTl + wid * 1024;
  char* kd1 = (char*)kTl + 4096 + wid * 1024;
  char* vd0 = (char*)vTl + wid * 1024;
  char* vd1 = (char*)vTl + 4096 + wid * 1024;

  float m_r[4], l_r[4];
  f32x4_t o_acc[4] = {};
#pragma unroll
  for (int r = 0; r < 4; ++r) { m_r[r] = -1e30f; l_r[r] = 0.f; }

  const int nkv = qi + 1;
  for (int it = 0; it < nkv; ++it) {
    const int kv0 = it * 64;
    gload16(ksrc0 + (size_t)kv0 * 1024, kd0);
    gload16(ksrc1 + (size_t)kv0 * 1024, kd1);
    gload16(vsrc0 + kv0, vd0);
    gload16(vsrc1 + kv0, vd1);
    __syncthreads();

    float sc[4][4];
    __builtin_amdgcn_s_setprio(1);
#pragma unroll
    for (int cf = 0; cf < 4; ++cf) {
      const int row = cf * 16 + ln;
      const int swz = row & 7;
      const bf16x8_t b0 = *(const bf16x8_t*)((char*)kTl + row * 128 + ((hi ^ swz) * 16));
      const bf16x8_t b1 = *(const bf16x8_t*)((char*)kTl + row * 128 + (((4 + hi) ^ swz) * 16));
      f32x4_t zacc = {};
      zacc = mfma16(aq0, b0, zacc);
      zacc = mfma16(aq1, b1, zacc);
#pragma unroll
      for (int r = 0; r < 4; ++r) sc[cf][r] = zacc[r] * 0.125f;
    }
    __builtin_amdgcn_s_setprio(0);
    if (kv0 + 63 > q0w) {
#pragma unroll
      for (int cf = 0; cf < 4; ++cf)
#pragma unroll
        for (int r = 0; r < 4; ++r) {
          const int qg = q0w + hi * 4 + r;
          const int kg = kv0 + cf * 16 + ln;
          if (kg > qg) sc[cf][r] = -1e30f;
        }
    }
#pragma unroll
    for (int r = 0; r < 4; ++r) {
      float tm = fmaxf(fmaxf(sc[0][r], sc[1][r]), fmaxf(sc[2][r], sc[3][r]));
      tm = fmaxf(tm, __shfl_xor(tm, 1));
      tm = fmaxf(tm, __shfl_xor(tm, 2));
      tm = fmaxf(tm, __shfl_xor(tm, 4));
      tm = fmaxf(tm, __shfl_xor(tm, 8));
      const float mn = fmaxf(m_r[r], tm);
      const float alpha = __expf(m_r[r] - mn);
      float rsum = 0.f;
#pragma unroll
      for (int cf = 0; cf < 4; ++cf) {
        const float p = __expf(sc[cf][r] - mn);
        sc[cf][r] = p; rsum += p;
      }
      rsum += __shfl_xor(rsum, 1); rsum += __shfl_xor(rsum, 2);
      rsum += __shfl_xor(rsum, 4); rsum += __shfl_xor(rsum, 8);
      l_r[r] = l_r[r] * alpha + rsum;
      m_r[r] = mn;
#pragma unroll
      for (int df = 0; df < 4; ++df) o_acc[df][r] *= alpha;
    }
    unsigned short* pw = &pl[wid][0];
#pragma unroll
    for (int cf = 0; cf < 4; ++cf)
#pragma unroll
      for (int r = 0; r < 4; ++r) {
        const int qq = hi * 4 + r;
        const int kv = cf * 16 + ln;
        const int bo = (qq * 128 + kv * 2) ^ ((qq & 7) << 4);
        *(unsigned short*)((char*)pw + bo) = f2bf(sc[cf][r]);
      }
    // P tile is wave-local: wave-order LDS ops only need lgkmcnt drain, not a block barrier.
    asm volatile("s_waitcnt lgkmcnt(0)" ::: "memory");
    __builtin_amdgcn_sched_barrier(0);
    const bf16x8_t pa0 = *(const bf16x8_t*)((char*)pw + ((ln * 128 + hi * 16) ^ ((ln & 7) << 4)));
    const bf16x8_t pa1 = *(const bf16x8_t*)((char*)pw + ((ln * 128 + 64 + hi * 16) ^ ((ln & 7) << 4)));
    __builtin_amdgcn_s_setprio(1);
#pragma unroll
    for (int df = 0; df < 4; ++df) {
      const int d = df * 16 + ln;
      const int swz = d & 7;
      const bf16x8_t bv0 = *(const bf16x8_t*)((char*)vTl + d * 128 + ((hi ^ swz) * 16));
      const bf16x8_t bv1 = *(const bf16x8_t*)((char*)vTl + d * 128 + (((4 + hi) ^ swz) * 16));
      o_acc[df] = mfma16(pa0, bv0, o_acc[df]);
      o_acc[df] = mfma16(pa1, bv1, o_acc[df]);
    }
    __builtin_amdgcn_s_setprio(0);
    __syncthreads();  // protects kTl/vTl reuse next iteration
  }
#pragma unroll
  for (int df = 0; df < 4; ++df) {
    const int n = h * 64 + df * 16 + ln;
#pragma unroll
    for (int r = 0; r < 4; ++r) {
      const int m = q0w + hi * 4 + r;
      ao[(size_t)m * 1024 + n] = f2bf(o_acc[df][r] / l_r[r]);
    }
  }
}

// ---------------- gating + LN2: writes h2 (bf16) AND top-2 routing ----------------
__global__ __launch_bounds__(256) void gate_kernel(const float* __restrict__ x2, const float* __restrict__ g,
                                                   const float* __restrict__ b, const float* __restrict__ wg,
                                                   unsigned short* __restrict__ h2o,
                                                   int2* __restrict__ te, float2* __restrict__ tw,
                                                   int* __restrict__ cnt) {
  const int tid = threadIdx.x, wid = tid >> 6, lane = tid & 63;
  const int t = blockIdx.x * 4 + wid;
  const float* row = x2 + (size_t)t * 1024;
  float vv[16];
#pragma unroll
  for (int i = 0; i < 4; ++i) *(float4*)&vv[i * 4] = *(const float4*)(row + lane * 16 + i * 4);
  float s = 0.f, s2 = 0.f;
#pragma unroll
  for (int j = 0; j < 16; ++j) { s += vv[j]; s2 += vv[j] * vv[j]; }
#pragma unroll
  for (int o = 1; o < 64; o <<= 1) { s += __shfl_xor(s, o); s2 += __shfl_xor(s2, o); }
  const float mu = s * 0.0009765625f;
  const float var = s2 * 0.0009765625f - mu * mu;
  const float rs = rsqrtf(var + 1e-5f);
  float acc[8] = {0.f, 0.f, 0.f, 0.f, 0.f, 0.f, 0.f, 0.f};
  bf16x8_t o0, o1;
#pragma unroll
  for (int j = 0; j < 16; ++j) {
    const int d = lane * 16 + j;
    const float xv = (vv[j] - mu) * rs * g[d] + b[d];
    if (j < 8) o0[j] = (short)f2bf(xv); else o1[j - 8] = (short)f2bf(xv);
    const float4 w0 = *(const float4*)(wg + d * 8);
    const float4 w1 = *(const float4*)(wg + d * 8 + 4);
    acc[0] += xv * w0.x; acc[1] += xv * w0.y; acc[2] += xv * w0.z; acc[3] += xv * w0.w;
    acc[4] += xv * w1.x; acc[5] += xv * w1.y; acc[6] += xv * w1.z; acc[7] += xv * w1.w;
  }
  // write LN2 row to h2 (replaces the separate ln2 pass); 2x16B per lane, coalesced
  *(bf16x8_t*)(h2o + (size_t)t * 1024 + lane * 16) = o0;
  *(bf16x8_t*)(h2o + (size_t)t * 1024 + lane * 16 + 8) = o1;
#pragma unroll
  for (int o = 1; o < 64; o <<= 1) {
#pragma unroll
    for (int e = 0; e < 8; ++e) acc[e] += __shfl_xor(acc[e], o);
  }
  if (lane == 0) {
    float sg[8];
#pragma unroll
    for (int e = 0; e < 8; ++e) sg[e] = 1.f / (1.f + __expf(-acc[e]));
    int e0 = 0;
#pragma unroll
    for (int e = 1; e < 8; ++e) if (sg[e] > sg[e0]) e0 = e;
    int e1 = (e0 == 0) ? 1 : 0;
#pragma unroll
    for (int e = 0; e < 8; ++e) if (e != e0 && sg[e] > sg[e1]) e1 = e;
    const float v0 = sg[e0], v1 = sg[e1];
    const float inv = 1.f / (v0 + v1 + 1e-9f);
    te[t] = make_int2(e0, e1);
    tw[t] = make_float2(v0 * inv, v1 * inv);
    atomicAdd(&cnt[e0], 1);
    atomicAdd(&cnt[e1], 1);
  }
}

__global__ void zero_counters(int* p) { if (threadIdx.x < 8) p[threadIdx.x] = 0; }

// ---------------- routing phase 2: 256-row tiles, padded offsets + metadata ----------------
__global__ __launch_bounds__(256) void g2_kernel(const int* __restrict__ cnt, int* __restrict__ slot_off,
                                                 int* __restrict__ tile_expert, int* __restrict__ tile_rowbase,
                                                 int* __restrict__ cursor, int* __restrict__ assign_token,
                                                 float* __restrict__ assign_w) {
  const int tid = threadIdx.x;
  for (int i = tid; i < 8192; i += 256) { assign_token[i] = -1; assign_w[i] = 0.f; }
  if (tid == 0) {
    int base = 0, tiles = 0;
    for (int e = 0; e < 8; ++e) {
      const int c = cnt[e];
      slot_off[e] = base;
      cursor[e] = 0;
      const int nt = (c + 255) >> 8;
      for (int i = 0; i < nt; ++i) {
        tile_expert[tiles] = e;
        tile_rowbase[tiles] = base + i * 256;
        ++tiles;
      }
      base += nt * 256;
    }
    for (; tiles < 40; ++tiles) tile_expert[tiles] = -1;
  }
}

// ---------------- routing phase 3: scatter assignments ----------------
__global__ __launch_bounds__(256) void g3_kernel(const int2* __restrict__ te, const float2* __restrict__ tw,
                                                 const int* __restrict__ slot_off, int* __restrict__ cursor,
                                                 int* __restrict__ assign_token, float* __restrict__ assign_w) {
  const int t = blockIdx.x * 256 + threadIdx.x;
  const int2 e = te[t];
  const float2 w = tw[t];
  const int s0 = slot_off[e.x] + atomicAdd(&cursor[e.x], 1);
  assign_token[s0] = t; assign_w[s0] = w.x;
  const int s1 = slot_off[e.y] + atomicAdd(&cursor[e.y], 1);
  assign_token[s1] = t; assign_w[s1] = w.y;
}

// ---- stage a 256x32 A tile (16KB) = 4 gload16 ----
DI void stageA4(const unsigned short* a0, const unsigned short* a1,
                const unsigned short* a2, const unsigned short* a3,
                int koff, char* Ab, int wid) {
  gload16(a0 + koff, Ab + wid * 1024);
  gload16(a1 + koff, Ab + 4096 + wid * 1024);
  gload16(a2 + koff, Ab + 8192 + wid * 1024);
  gload16(a3 + koff, Ab + 12288 + wid * 1024);
}
// ---- stage a 128x32 A tile (8KB) = 2 gload16 ----
DI void stageA2(const unsigned short* a0, const unsigned short* a1,
                int koff, char* Ab, int wid) {
  gload16(a0 + koff, Ab + wid * 1024);
  gload16(a1 + koff, Ab + 4096 + wid * 1024);
}

// ---- upgate helpers (BM=256) ----
DI void ug_write_b(char* Bn, const int* boff, const float4& q0, const float4& q1,
                   const float4& q2, const float4& q3) {
  const float* q0p = (const float*)&q0; const float* q1p = (const float*)&q1;
  const float* q2p = (const float*)&q2; const float* q3p = (const float*)&q3;
#pragma unroll
  for (int i = 0; i < 4; ++i) {
    uint2 w;
    w.x = pk2(q0p[i], q1p[i]);
    w.y = pk2(q2p[i], q3p[i]);
    *(uint2*)(Bn + boff[i]) = w;
  }
}

DI void ug_mfma256(const unsigned short* A, const char* Bb, int wr, int wc, int ln, int hi,
                   f32x4_t (&accg)[8][2], f32x4_t (&accu)[8][2]) {
  bf16x8_t af[8];
#pragma unroll
  for (int mf = 0; mf < 8; ++mf)
    af[mf] = frag(A, wr * 128 + mf * 16 + ln, hi);
  __builtin_amdgcn_s_setprio(1);
#pragma unroll
  for (int nf = 0; nf < 2; ++nf) {
    const int nrow = wc * 32 + nf * 16 + ln;
    int bo = nrow * 64 + hi * 16;
    bo ^= ((nrow >> 2) & 7) << 4;
    const bf16x8_t bg = *(const bf16x8_t*)(Bb + bo);
    const bf16x8_t bu = *(const bf16x8_t*)(Bb + 4096 + bo);
#pragma unroll
    for (int mf = 0; mf < 8; ++mf) {
      accg[mf][nf] = mfma16(af[mf], bg, accg[mf][nf]);
      accu[mf][nf] = mfma16(af[mf], bu, accu[mf][nf]);
    }
  }
  __builtin_amdgcn_s_setprio(0);
}

// ---------------- MoE up+gate: BM=256, A-first issue order (race-free 2-deep B) ----------
__global__ __launch_bounds__(256, 2) void upgate_kernel(const unsigned short* __restrict__ h2,
                                                        const float* __restrict__ w_eg, const float* __restrict__ w_eu,
                                                        const int* __restrict__ tile_expert,
                                                        const int* __restrict__ tile_rowbase,
                                                        const int* __restrict__ assign_token,
                                                        unsigned short* __restrict__ act) {
  const int by = blockIdx.y;
  const int e = tile_expert[by];
  if (e < 0) return;
  const int n0 = blockIdx.x * 64;
  const int rowbase = tile_rowbase[by];
  const int tid = threadIdx.x;
  __shared__ unsigned short lds[2 * 8192 + 2 * 4096];  // A dbuf 2x16KB, B dbuf 2x8KB
  char* A0 = (char*)lds;
  char* A1 = (char*)lds + 16384;
  char* B0 = (char*)lds + 32768;
  char* B1 = (char*)lds + 40960;
  const int wid = tid >> 6, lane = tid & 63, ln = lane & 15, hi = lane >> 4;
  const int wr = wid >> 1, wc = wid & 1;
  const int r0s = rowbase + (tid >> 2);
  int tk0 = assign_token[r0s];        tk0 = tk0 < 0 ? 0 : tk0;
  int tk1 = assign_token[r0s + 64];   tk1 = tk1 < 0 ? 0 : tk1;
  int tk2 = assign_token[r0s + 128];  tk2 = tk2 < 0 ? 0 : tk2;
  int tk3 = assign_token[r0s + 192];  tk3 = tk3 < 0 ? 0 : tk3;
  const int cs = chunk_swz(tid);
  const unsigned short* aR0 = h2 + (size_t)tk0 * 1024 + cs;
  const unsigned short* aR1 = h2 + (size_t)tk1 * 1024 + cs;
  const unsigned short* aR2 = h2 + (size_t)tk2 * 1024 + cs;
  const unsigned short* aR3 = h2 + (size_t)tk3 * 1024 + cs;
  const int mat = tid >> 7;
  const int blk = tid & 127;
  const int kb = (blk >> 4) * 4;
  const int nb = (blk & 15) * 4;
  const float* bsrc = (mat ? w_eu : w_eg) + (size_t)e * 1024 * 4096 + (size_t)kb * 4096 + n0 + nb;
  int boff[4];
#pragma unroll
  for (int i = 0; i < 4; ++i) {
    const int n = nb + i;
    int bo = mat * 4096 + n * 64 + kb * 2;
    bo ^= ((n >> 2) & 7) << 4;
    boff[i] = bo;
  }
  f32x4_t accg[8][2] = {};
  f32x4_t accu[8][2] = {};
  float4 qA0, qA1, qA2, qA3, qB0, qB1, qB2, qB3;
  // ---- prologue: A(0)->A0; B(0)->regs; write B0 (drains A(0) too, FIFO); B(1)->qA ----
  stageA4(aR0, aR1, aR2, aR3, 0, A0, wid);
  qB0 = *(const float4*)(bsrc);
  qB1 = *(const float4*)(bsrc + 4096);
  qB2 = *(const float4*)(bsrc + 8192);
  qB3 = *(const float4*)(bsrc + 12288);
  __builtin_amdgcn_sched_barrier(0);
  ug_write_b(B0, boff, qB0, qB1, qB2, qB3);
  {
    const float* bs = bsrc + (size_t)32 * 4096;
    qA0 = *(const float4*)(bs);
    qA1 = *(const float4*)(bs + 4096);
    qA2 = *(const float4*)(bs + 8192);
    qA3 = *(const float4*)(bs + 12288);
  }
  asm volatile("s_waitcnt lgkmcnt(0)" ::: "memory");
  __builtin_amdgcn_sched_barrier(0);
  __builtin_amdgcn_s_barrier();
  // ---- main: t = 0..29 (15 pairs) ----
  for (int p = 0; p < 15; ++p) {
    {  // even t=2p: compute A0/B0; stage A(t+1)->A1; load B(t+2)->qB
      const int t = 2 * p;
      stageA4(aR0, aR1, aR2, aR3, (t + 1) * 32, A1, wid);
      const float* bs = bsrc + (size_t)(t + 2) * 32 * 4096;
      qB0 = *(const float4*)(bs);
      qB1 = *(const float4*)(bs + 4096);
      qB2 = *(const float4*)(bs + 8192);
      qB3 = *(const float4*)(bs + 12288);
      __builtin_amdgcn_sched_barrier(0);
      ug_write_b(B1, boff, qA0, qA1, qA2, qA3);   // implied vmcnt(8): keeps A(t+1)+B(t+2)
      ug_mfma256((const unsigned short*)A0, B0, wr, wc, ln, hi, accg, accu);
      asm volatile("s_waitcnt vmcnt(4)" ::: "memory");  // retire A(t+1)x4; keep B(t+2)x4
      __builtin_amdgcn_sched_barrier(0);
      asm volatile("s_waitcnt lgkmcnt(0)" ::: "memory");
      __builtin_amdgcn_sched_barrier(0);
      __builtin_amdgcn_s_barrier();
    }
    {  // odd t=2p+1: compute A1/B1
      const int t = 2 * p + 1;
      stageA4(aR0, aR1, aR2, aR3, (t + 1) * 32, A0, wid);
      const float* bs = bsrc + (size_t)(t + 2) * 32 * 4096;
      qA0 = *(const float4*)(bs);
      qA1 = *(const float4*)(bs + 4096);
      qA2 = *(const float4*)(bs + 8192);
      qA3 = *(const float4*)(bs + 12288);
      __builtin_amdgcn_sched_barrier(0);
      ug_write_b(B0, boff, qB0, qB1, qB2, qB3);
      ug_mfma256((const unsigned short*)A1, B1, wr, wc, ln, hi, accg, accu);
      asm volatile("s_waitcnt vmcnt(4)" ::: "memory");
      __builtin_amdgcn_sched_barrier(0);
      asm volatile("s_waitcnt lgkmcnt(0)" ::: "memory");
      __builtin_amdgcn_sched_barrier(0);
      __builtin_amdgcn_s_barrier();
    }
  }
  // ---- t=30 (A0/B0): stage A(31)->A1; write B(31) from qA; drain all ----
  stageA4(aR0, aR1, aR2, aR3, 31 * 32, A1, wid);
  __builtin_amdgcn_sched_barrier(0);
  ug_write_b(B1, boff, qA0, qA1, qA2, qA3);   // implied vmcnt(4): keeps A(31)
  ug_mfma256((const unsigned short*)A0, B0, wr, wc, ln, hi, accg, accu);
  asm volatile("s_waitcnt vmcnt(0)" ::: "memory");
  __builtin_amdgcn_sched_barrier(0);
  asm volatile("s_waitcnt lgkmcnt(0)" ::: "memory");
  __builtin_amdgcn_sched_barrier(0);
  __builtin_amdgcn_s_barrier();
  // ---- t=31: MFMA only ----
  ug_mfma256((const unsigned short*)A1, B1, wr, wc, ln, hi, accg, accu);
#pragma unroll
  for (int mf = 0; mf < 8; ++mf)
#pragma unroll
    for (int nf = 0; nf < 2; ++nf)
#pragma unroll
      for (int r = 0; r < 4; ++r) {
        const int m = wr * 128 + mf * 16 + hi * 4 + r;
        const int n = n0 + wc * 32 + nf * 16 + ln;
        const float gv = accg[mf][nf][r], uv = accu[mf][nf][r];
        const float val = gv / (1.f + __expf(-gv)) * uv;
        act[(size_t)(rowbase + m) * 4096 + n] = f2bf(val);
      }
}

// ---- down helpers (BM=128) ----
DI void dn_write_b(char* Bn, const int* boff, const float4& q0, const float4& q1) {
  const float* q0p = (const float*)&q0; const float* q1p = (const float*)&q1;
#pragma unroll
  for (int i = 0; i < 4; ++i)
    *(uint32_t*)(Bn + boff[i]) = pk2(q0p[i], q1p[i]);
}

DI void dn_mfma(const unsigned short* A, const char* Bb, int wr, int wc, int ln, int hi,
                f32x4_t (&acc)[4][2]) {
  bf16x8_t af[4];
#pragma unroll
  for (int mf = 0; mf < 4; ++mf)
    af[mf] = frag(A, wr * 64 + mf * 16 + ln, hi);
  __builtin_amdgcn_s_setprio(1);
#pragma unroll
  for (int nf = 0; nf < 2; ++nf) {
    const int nrow = wc * 32 + nf * 16 + ln;
    int bo = nrow * 64 + hi * 16;
    bo ^= ((nrow >> 2) & 7) << 4;
    const bf16x8_t bb = *(const bf16x8_t*)(Bb + bo);
#pragma unroll
    for (int mf = 0; mf < 4; ++mf)
      acc[mf][nf] = mfma16(af[mf], bb, acc[mf][nf]);
  }
  __builtin_amdgcn_s_setprio(0);
}

// ---------------- MoE down: BM=128, split-K x4 (free via atomicAdd), A-first order --------
// grid (16 n0, 48 half-tiles, 4 kz); each block: K-slice of 1024 (32 steps).
__global__ __launch_bounds__(256) void down_kernel(const unsigned short* __restrict__ act,
                                                   const float* __restrict__ w_ed,
                                                   const int* __restrict__ tile_expert,
                                                   const int* __restrict__ tile_rowbase,
                                                   const int* __restrict__ assign_token,
                                                   const float* __restrict__ assign_w,
                                                   float* __restrict__ out) {
  const int tix = blockIdx.y;
  const int e = tile_expert[tix >> 1];
  if (e < 0) return;
  const int rowbase = tile_rowbase[tix >> 1] + (tix & 1) * 128;
  const int n0 = blockIdx.x * 64;
  const int kz = blockIdx.z * 1024;
  const int tid = threadIdx.x;
  __shared__ unsigned short lds[2 * 4096 + 2 * 2048];  // A dbuf 2x8KB, B dbuf 2x4KB
  char* A0 = (char*)lds;
  char* A1 = (char*)lds + 8192;
  char* B0 = (char*)lds + 16384;
  char* B1 = (char*)lds + 20480;
  const int wid = tid >> 6, lane = tid & 63, ln = lane & 15, hi = lane >> 4;
  const int wr = wid >> 1, wc = wid & 1;
  const int cs = chunk_swz(tid);
  const unsigned short* aR0 = act + (size_t)(rowbase + (tid >> 2)) * 4096 + kz + cs;
  const unsigned short* aR1 = aR0 + (size_t)64 * 4096;
  const int nb = (tid & 15) * 4;
  const int kb2 = (tid >> 4) * 2;
  const float* bsrc = w_ed + (size_t)e * 4096 * 1024 + (size_t)(kz + kb2) * 1024 + n0 + nb;
  int boff[4];
#pragma unroll
  for (int i = 0; i < 4; ++i) {
    const int n = nb + i;
    int bo = n * 64 + kb2 * 2;
    bo ^= ((n >> 2) & 7) << 4;
    boff[i] = bo;
  }
  f32x4_t acc[4][2] = {};
  float4 qA0, qA1, qB0, qB1;
  // ---- prologue ----
  stageA2(aR0, aR1, 0, A0, wid);
  qB0 = *(const float4*)(bsrc);
  qB1 = *(const float4*)(bsrc + 1024);
  __builtin_amdgcn_sched_barrier(0);
  dn_write_b(B0, boff, qB0, qB1);   // implied wait drains A(0) too (older in FIFO)
  {
    const float* bs = bsrc + (size_t)32 * 1024;
    qA0 = *(const float4*)(bs);
    qA1 = *(const float4*)(bs + 1024);
  }
  asm volatile("s_waitcnt lgkmcnt(0)" ::: "memory");
  __builtin_amdgcn_sched_barrier(0);
  __builtin_amdgcn_s_barrier();
  // ---- main: t = 0..29 (15 pairs) ----
  for (int p = 0; p < 15; ++p) {
    {  // even t=2p
      const int t = 2 * p;
      stageA2(aR0, aR1, (t + 1) * 32, A1, wid);
      const float* bs = bsrc + (size_t)(t + 2) * 32 * 1024;
      qB0 = *(const float4*)(bs);
      qB1 = *(const float4*)(bs + 1024);
      __builtin_amdgcn_sched_barrier(0);
      dn_write_b(B1, boff, qA0, qA1);   // implied vmcnt(4): keeps A(t+1)x2 + B(t+2)x2
      dn_mfma((const unsigned short*)A0, B0, wr, wc, ln, hi, acc);
      asm volatile("s_waitcnt vmcnt(2)" ::: "memory");  // retire A(t+1); keep B(t+2)
      __builtin_amdgcn_sched_barrier(0);
      asm volatile("s_waitcnt lgkmcnt(0)" ::: "memory");
      __builtin_amdgcn_sched_barrier(0);
      __builtin_amdgcn_s_barrier();
    }
    {  // odd t=2p+1
      const int t = 2 * p + 1;
      stageA2(aR0, aR1, (t + 1) * 32, A0, wid);
      const float* bs = bsrc + (size_t)(t + 2) * 32 * 1024;
      qA0 = *(const float4*)(bs);
      qA1 = *(const float4*)(bs + 1024);
      __builtin_amdgcn_sched_barrier(0);
      dn_write_b(B0, boff, qB0, qB1);
      dn_mfma((const unsigned short*)A1, B1, wr, wc, ln, hi, acc);
      asm volatile("s_waitcnt vmcnt(2)" ::: "memory");
      __builtin_amdgcn_sched_barrier(0);
      asm volatile("s_waitcnt lgkmcnt(0)" ::: "memory");
      __builtin_amdgcn_sched_barrier(0);
      __builtin_amdgcn_s_barrier();
    }
  }
  // ---- t=30: stage A(31); write B(31) from qA; drain ----
  stageA2(aR0, aR1, 31 * 32, A1, wid);
  __builtin_amdgcn_sched_barrier(0);
  dn_write_b(B1, boff, qA0, qA1);
  dn_mfma((const unsigned short*)A0, B0, wr, wc, ln, hi, acc);
  asm volatile("s_waitcnt vmcnt(0)" ::: "memory");
  __builtin_amdgcn_sched_barrier(0);
  asm volatile("s_waitcnt lgkmcnt(0)" ::: "memory");
  __builtin_amdgcn_sched_barrier(0);
  __builtin_amdgcn_s_barrier();
  // ---- t=31 ----
  dn_mfma((const unsigned short*)A1, B1, wr, wc, ln, hi, acc);
#pragma unroll
  for (int mf = 0; mf < 4; ++mf)
#pragma unroll
    for (int r = 0; r < 4; ++r) {
      const int m = wr * 64 + mf * 16 + hi * 4 + r;
      const int slot = rowbase + m;
      const int tk = assign_token[slot];
      if (tk >= 0) {
        const float w = assign_w[slot];
#pragma unroll
        for (int nf = 0; nf < 2; ++nf) {
          const int n = n0 + wc * 32 + nf * 16 + ln;
          atomicAdd(out + (size_t)tk * 1024 + n, acc[mf][nf][r] * w);
        }
      }
    }
}

// ---------------- host launcher ----------------
extern "C" void kernel_launch(void* const* d_in, const int* in_sizes, int n_in,
                              void* d_out, int out_size, void* d_ws, size_t ws_size,
                              hipStream_t stream) {
  (void)in_sizes; (void)n_in; (void)out_size;
  const float* x    = (const float*)d_in[0];
  const float* ln1g = (const float*)d_in[1];
  const float* ln1b = (const float*)d_in[2];
  const float* wq   = (const float*)d_in[3];
  const float* wk   = (const float*)d_in[4];
  const float* wv   = (const float*)d_in[5];
  const float* wo   = (const float*)d_in[6];
  const float* ln2g = (const float*)d_in[7];
  const float* ln2b = (const float*)d_in[8];
  const float* wg   = (const float*)d_in[9];
  const float* weg  = (const float*)d_in[10];
  const float* weu  = (const float*)d_in[11];
  const float* wed  = (const float*)d_in[12];
  float* out = (float*)d_out;
  char* ws = (char*)d_ws;

  const size_t MB = (size_t)1 << 20;
  if (ws_size < 86 * MB) return;
  unsigned short* wqT = (unsigned short*)(ws + 0 * MB);
  unsigned short* wkT = (unsigned short*)(ws + 2 * MB);
  unsigned short* wvT = (unsigned short*)(ws + 4 * MB);
  unsigned short* woT = (unsigned short*)(ws + 6 * MB);
  unsigned short* h1  = (unsigned short*)(ws + 8 * MB);
  unsigned short* qb  = (unsigned short*)(ws + 12 * MB);
  unsigned short* kbf = (unsigned short*)(ws + 16 * MB);
  unsigned short* vt  = (unsigned short*)(ws + 20 * MB);
  unsigned short* ao  = (unsigned short*)(ws + 24 * MB);
  unsigned short* h2  = (unsigned short*)(ws + 28 * MB);
  unsigned short* act = (unsigned short*)(ws + 32 * MB);  // 6144*4096*2 = 48MiB (52MB slot)
  int2*   te = (int2*)(ws + 84 * MB);
  float2* tw = (float2*)(ws + 84 * MB + 16384);
  int*  meta = (int*)(ws + 84 * MB + 32768);
  int* cnt = meta;
  int* cursor = meta + 8;
  int* slot_off = meta + 16;
  int* tile_expert = meta + 24;
  int* tile_rowbase = meta + 64;
  int*   assign_token = (int*)(ws + 84 * MB + 36864);
  float* assign_w     = (float*)(ws + 84 * MB + 36864 + 32768);

  zero_counters<<<1, 64, 0, stream>>>(cnt);
  transpose_cvt4<<<dim3(16, 16, 4), 256, 0, stream>>>(wq, wk, wv, wo, wqT, wkT, wvT, woT);
  ln_kernel<<<2048, 256, 0, stream>>>(x, ln1g, ln1b, h1);
  qkv_kernel<<<dim3(8, 16, 3), 256, 0, stream>>>(h1, wqT, wkT, wvT, qb, kbf, vt);
  attn_kernel<<<dim3(32, 16), 256, 0, stream>>>(qb, kbf, vt, ao);
  wo_kernel<<<dim3(16, 16), 256, 0, stream>>>(ao, woT, x, out);
  gate_kernel<<<512, 256, 0, stream>>>(out, ln2g, ln2b, wg, h2, te, tw, cnt);
  g2_kernel<<<1, 256, 0, stream>>>(cnt, slot_off, tile_expert, tile_rowbase, cursor, assign_token, assign_w);
  g3_kernel<<<8, 256, 0, stream>>>(te, tw, slot_off, cursor, assign_token, assign_w);
  upgate_kernel<<<dim3(64, 24), 256, 0, stream>>>(h2, weg, weu, tile_expert, tile_rowbase, assign_token, act);
  down_kernel<<<dim3(16, 48, 4), 256, 0, stream>>>(act, wed, tile_expert, tile_rowbase, assign_token, assign_w, out);
}

// Round 16
// 480.074 us; speedup vs baseline: 1.0560x; 1.0023x over previous
//
#include <hip/hip_runtime.h>
#include <hip/hip_bf16.h>
#include <stdint.h>

#define DI __device__ __forceinline__

typedef short bf16x8_t __attribute__((ext_vector_type(8)));
typedef float f32x4_t __attribute__((ext_vector_type(4)));

DI unsigned short f2bf(float f) {
  __hip_bfloat16 h = __float2bfloat16(f);
  unsigned short u;
  __builtin_memcpy(&u, &h, 2);
  return u;
}

// pair f32 -> packed 2xbf16 (compiler emits v_cvt_pk_bf16_f32)
DI uint32_t pk2(float a, float b) {
  return (uint32_t)f2bf(a) | ((uint32_t)f2bf(b) << 16);
}

DI f32x4_t mfma16(bf16x8_t a, bf16x8_t b, f32x4_t c) {
  return __builtin_amdgcn_mfma_f32_16x16x32_bf16(a, b, c, 0, 0, 0);
}

DI void gload16(const void* g, void* l) {
  __builtin_amdgcn_global_load_lds(
      (const __attribute__((address_space(1))) uint32_t*)g,
      (__attribute__((address_space(3))) uint32_t*)l, 16, 0, 0);
}

// A/B tile fragment read with chunk swizzle matching pre-swizzled global source:
// lds[row][chunk ^ ((row>>1)&3)], tile row = 32 shorts (64B), chunk = 8 shorts (16B)
DI bf16x8_t frag(const unsigned short* base, int row, int hi) {
  return *(const bf16x8_t*)&base[row * 32 + ((hi ^ ((row >> 1) & 3)) * 8)];
}
// per-lane source chunk offset (in shorts) for gload16 A/B staging
DI int chunk_swz(int tid) { return ((tid & 3) ^ ((tid >> 3) & 3)) * 8; }

// ---------------- fused transpose + f32->bf16 for 4 square matrices (z selects) ----------
__global__ __launch_bounds__(256) void transpose_cvt4(const float* __restrict__ s0, const float* __restrict__ s1,
                                                      const float* __restrict__ s2, const float* __restrict__ s3,
                                                      unsigned short* __restrict__ d0, unsigned short* __restrict__ d1,
                                                      unsigned short* __restrict__ d2, unsigned short* __restrict__ d3) {
  __shared__ float tile[64][65];
  const int z = blockIdx.z;
  const float* in = (z == 0) ? s0 : (z == 1) ? s1 : (z == 2) ? s2 : s3;
  unsigned short* out = (z == 0) ? d0 : (z == 1) ? d1 : (z == 2) ? d2 : d3;
  const int tid = threadIdx.x;
  const int tx = tid & 15, ty = tid >> 4;
  const int r0 = blockIdx.y * 64, c0 = blockIdx.x * 64;
#pragma unroll
  for (int i = 0; i < 4; ++i) {
    const int r = ty + i * 16;
    const float4 v = *(const float4*)(in + (size_t)(r0 + r) * 1024 + c0 + tx * 4);
    tile[r][tx * 4 + 0] = v.x; tile[r][tx * 4 + 1] = v.y;
    tile[r][tx * 4 + 2] = v.z; tile[r][tx * 4 + 3] = v.w;
  }
  __syncthreads();
#pragma unroll
  for (int i = 0; i < 4; ++i) {
    const int r = ty + i * 16;
    ushort4 o;
    o.x = f2bf(tile[tx * 4 + 0][r]); o.y = f2bf(tile[tx * 4 + 1][r]);
    o.z = f2bf(tile[tx * 4 + 2][r]); o.w = f2bf(tile[tx * 4 + 3][r]);
    *(ushort4*)(out + (size_t)(c0 + r) * 1024 + r0 + tx * 4) = o;
  }
}

// ---------------- LayerNorm f32 -> bf16 (used for LN1 only) ----------------
__global__ __launch_bounds__(256) void ln_kernel(const float* __restrict__ x, const float* __restrict__ g,
                                                 const float* __restrict__ b, unsigned short* __restrict__ out) {
  const int row = blockIdx.x, tid = threadIdx.x;
  const int wid = tid >> 6, lane = tid & 63;
  const float4 v = *(const float4*)(x + (size_t)row * 1024 + tid * 4);
  float s = v.x + v.y + v.z + v.w;
  float s2 = v.x * v.x + v.y * v.y + v.z * v.z + v.w * v.w;
#pragma unroll
  for (int o = 1; o < 64; o <<= 1) { s += __shfl_xor(s, o); s2 += __shfl_xor(s2, o); }
  __shared__ float red[8];
  if (lane == 0) { red[wid] = s; red[4 + wid] = s2; }
  __syncthreads();
  const float ts = red[0] + red[1] + red[2] + red[3];
  const float ts2 = red[4] + red[5] + red[6] + red[7];
  const float mu = ts * 0.0009765625f;
  const float var = ts2 * 0.0009765625f - mu * mu;
  const float rs = rsqrtf(var + 1e-5f);
  const float4 gg = *(const float4*)(g + tid * 4);
  const float4 bb = *(const float4*)(b + tid * 4);
  ushort4 o4;
  o4.x = f2bf((v.x - mu) * rs * gg.x + bb.x);
  o4.y = f2bf((v.y - mu) * rs * gg.y + bb.y);
  o4.z = f2bf((v.z - mu) * rs * gg.z + bb.z);
  o4.w = f2bf((v.w - mu) * rs * gg.w + bb.w);
  *(ushort4*)(out + (size_t)row * 1024 + tid * 4) = o4;
}

// ---------------- generic bf16 GEMM core: BM=128, BK=32, 256 thr, waves 2x2 ---------------
// 2-phase pipeline (T3 minimum): STAGE(t+1)->buf^1 issued BEFORE compute(t); one barrier
// per K-step whose built-in vmcnt(0)/lgkm(0) drain is covered by the MFMA section.
// LDS layout (shorts): A0[4096] A1[4096] B0[BSZ] B1[BSZ].
template<int BN>
DI void gemm_loop(const unsigned short* aR0, const unsigned short* aR1,
                  const unsigned short* bR0, const unsigned short* bR1,
                  const int K, unsigned short* lds, const int tid,
                  f32x4_t (&acc)[4][BN / 32]) {
  constexpr int NF = BN / 32;
  constexpr int BSZ = (BN == 128) ? 4096 : 2048;  // shorts per B buffer
  const int wid = tid >> 6, lane = tid & 63, ln = lane & 15, hi = lane >> 4;
  const int wr = wid >> 1, wc = wid & 1;
  const int nk = K >> 5;
  // stage tile 0 into buffer 0
  {
    char* Ab = (char*)lds;
    char* Bb = (char*)lds + 16384;
    gload16(aR0, Ab + wid * 1024);
    gload16(aR1, Ab + 4096 + wid * 1024);
    gload16(bR0, Bb + wid * 1024);
    if constexpr (BN == 128) gload16(bR1, Bb + 4096 + wid * 1024);
  }
  __syncthreads();
  for (int t = 0; t < nk; ++t) {
    if (t + 1 < nk) {  // prefetch next tile into the other buffer (uniform cond)
      const int k0 = (t + 1) << 5;
      const int b = (t + 1) & 1;
      char* Ab = (char*)lds + b * 8192;
      char* Bb = (char*)lds + 16384 + b * (BSZ * 2);
      gload16(aR0 + k0, Ab + wid * 1024);
      gload16(aR1 + k0, Ab + 4096 + wid * 1024);
      gload16(bR0 + k0, Bb + wid * 1024);
      if constexpr (BN == 128) gload16(bR1 + k0, Bb + 4096 + wid * 1024);
    }
    const unsigned short* A = lds + (t & 1) * 4096;
    const unsigned short* B = lds + 8192 + (t & 1) * BSZ;
    bf16x8_t af[4];
#pragma unroll
    for (int mf = 0; mf < 4; ++mf)
      af[mf] = frag(A, wr * 64 + mf * 16 + ln, hi);
    __builtin_amdgcn_s_setprio(1);
#pragma unroll
    for (int nf = 0; nf < NF; ++nf) {
      bf16x8_t bfr = frag(B, wc * (BN / 2) + nf * 16 + ln, hi);
#pragma unroll
      for (int mf = 0; mf < 4; ++mf)
        acc[mf][nf] = mfma16(af[mf], bfr, acc[mf][nf]);
    }
    __builtin_amdgcn_s_setprio(0);
    __syncthreads();  // drains prefetch (covered by compute) + WAR protection
  }
}

// ---------------- QKV projections (z = 0:Q, 1:K, 2:V-transposed) ----------------
__global__ __launch_bounds__(256) void qkv_kernel(const unsigned short* __restrict__ h1,
                                                  const unsigned short* __restrict__ wqT,
                                                  const unsigned short* __restrict__ wkT,
                                                  const unsigned short* __restrict__ wvT,
                                                  unsigned short* __restrict__ qb,
                                                  unsigned short* __restrict__ kbf,
                                                  unsigned short* __restrict__ vt) {
  __shared__ unsigned short lds[16384];  // A dbuf 16KB + B dbuf 16KB
  const int tid = threadIdx.x;
  const int z = blockIdx.z;
  const unsigned short* BT = (z == 0) ? wqT : (z == 1) ? wkT : wvT;
  const int m0 = blockIdx.y * 128, n0 = blockIdx.x * 128;
  f32x4_t acc[4][4] = {};
  const int cs = chunk_swz(tid);
  const unsigned short* aR0 = h1 + (size_t)(m0 + (tid >> 2)) * 1024 + cs;
  const unsigned short* aR1 = aR0 + 64 * 1024;
  const unsigned short* bR0 = BT + (size_t)(n0 + (tid >> 2)) * 1024 + cs;
  const unsigned short* bR1 = bR0 + 64 * 1024;
  gemm_loop<128>(aR0, aR1, bR0, bR1, 1024, lds, tid, acc);
  const int lane = tid & 63, ln = lane & 15, hi = lane >> 4, wid = tid >> 6;
  const int wr = wid >> 1, wc = wid & 1;
  if (z < 2) {
    unsigned short* o = z ? kbf : qb;
#pragma unroll
    for (int mf = 0; mf < 4; ++mf)
#pragma unroll
      for (int nf = 0; nf < 4; ++nf)
#pragma unroll
        for (int r = 0; r < 4; ++r) {
          const int m = m0 + wr * 64 + mf * 16 + hi * 4 + r;
          const int n = n0 + wc * 64 + nf * 16 + ln;
          o[(size_t)m * 1024 + n] = f2bf(acc[mf][nf][r]);
        }
  } else {
#pragma unroll
    for (int mf = 0; mf < 4; ++mf)
#pragma unroll
      for (int nf = 0; nf < 4; ++nf) {
        const int n = n0 + wc * 64 + nf * 16 + ln;
        const int mb = m0 + wr * 64 + mf * 16 + hi * 4;
        ushort4 o;
        o.x = f2bf(acc[mf][nf][0]); o.y = f2bf(acc[mf][nf][1]);
        o.z = f2bf(acc[mf][nf][2]); o.w = f2bf(acc[mf][nf][3]);
        *(ushort4*)(vt + (size_t)n * 2048 + mb) = o;
      }
  }
}

// ---------------- output projection + residual -> f32 d_out ----------------
__global__ __launch_bounds__(256) void wo_kernel(const unsigned short* __restrict__ ao,
                                                 const unsigned short* __restrict__ woT,
                                                 const float* __restrict__ x,
                                                 float* __restrict__ out) {
  __shared__ unsigned short lds[12288];  // A dbuf 16KB + B dbuf 8KB
  const int tid = threadIdx.x;
  const int m0 = blockIdx.y * 128, n0 = blockIdx.x * 64;
  f32x4_t acc[4][2] = {};
  const int cs = chunk_swz(tid);
  const unsigned short* aR0 = ao + (size_t)(m0 + (tid >> 2)) * 1024 + cs;
  const unsigned short* aR1 = aR0 + 64 * 1024;
  const unsigned short* bR0 = woT + (size_t)(n0 + (tid >> 2)) * 1024 + cs;
  gemm_loop<64>(aR0, aR1, bR0, nullptr, 1024, lds, tid, acc);
  const int lane = tid & 63, ln = lane & 15, hi = lane >> 4, wid = tid >> 6;
  const int wr = wid >> 1, wc = wid & 1;
#pragma unroll
  for (int mf = 0; mf < 4; ++mf)
#pragma unroll
    for (int nf = 0; nf < 2; ++nf)
#pragma unroll
      for (int r = 0; r < 4; ++r) {
        const int m = m0 + wr * 64 + mf * 16 + hi * 4 + r;
        const int n = n0 + wc * 32 + nf * 16 + ln;
        out[(size_t)m * 1024 + n] = acc[mf][nf][r] + x[(size_t)m * 1024 + n];
      }
}

// ---------------- flash attention, causal, head_dim 64 ----------------
// 2-phase pipeline: prefetch KV tile t+1 into the other buffer BEFORE compute(t);
// one barrier/iter (drain covered by QK^T+softmax+PV). Complementary-pair q-tile
// remap balances causal load across co-resident blocks. P round-trip is wave-local.
__global__ __launch_bounds__(256) void attn_kernel(const unsigned short* __restrict__ qb,
                                                   const unsigned short* __restrict__ kbuf,
                                                   const unsigned short* __restrict__ vt,
                                                   unsigned short* __restrict__ ao) {
  __shared__ unsigned short kTl[8192];  // 2 x (64 rows x 64 cols)
  __shared__ unsigned short vTl[8192];  // 2 x (64 d x 64 kv)
  __shared__ unsigned short pl[4][1024];
  const int tid = threadIdx.x;
  const int wid = tid >> 6, lane = tid & 63;
  const int ln = lane & 15, hi = lane >> 4;
  const int h = blockIdx.y;
  const int qi = (h < 8) ? blockIdx.x : (31 - blockIdx.x);
  const int q0 = qi * 64;
  const int q0w = q0 + wid * 16;

  const unsigned short* qrow = qb + (size_t)(q0w + ln) * 1024 + h * 64 + hi * 8;
  const bf16x8_t aq0 = *(const bf16x8_t*)(qrow);
  const bf16x8_t aq1 = *(const bf16x8_t*)(qrow + 32);

  const int str_r = tid >> 3, str_c = tid & 7;
  const int swc = (str_c ^ (str_r & 7)) * 8;
  const unsigned short* ksrc0 = kbuf + (size_t)str_r * 1024 + h * 64 + swc;
  const unsigned short* ksrc1 = kbuf + (size_t)(str_r + 32) * 1024 + h * 64 + swc;
  const unsigned short* vsrc0 = vt + (size_t)(h * 64 + str_r) * 2048 + swc;
  const unsigned short* vsrc1 = vt + (size_t)(h * 64 + str_r + 32) * 2048 + swc;

  float m_r[4], l_r[4];
  f32x4_t o_acc[4] = {};
#pragma unroll
  for (int r = 0; r < 4; ++r) { m_r[r] = -1e30f; l_r[r] = 0.f; }

  const int nkv = qi + 1;
  // stage KV tile 0 into buffer 0
  {
    char* kd = (char*)kTl;
    char* vd = (char*)vTl;
    gload16(ksrc0, kd + wid * 1024);
    gload16(ksrc1, kd + 4096 + wid * 1024);
    gload16(vsrc0, vd + wid * 1024);
    gload16(vsrc1, vd + 4096 + wid * 1024);
  }
  __syncthreads();
  for (int it = 0; it < nkv; ++it) {
    if (it + 1 < nkv) {  // prefetch next KV tile (uniform cond)
      const int kvn = (it + 1) * 64;
      const int b = (it + 1) & 1;
      char* kd = (char*)kTl + b * 8192;
      char* vd = (char*)vTl + b * 8192;
      gload16(ksrc0 + (size_t)kvn * 1024, kd + wid * 1024);
      gload16(ksrc1 + (size_t)kvn * 1024, kd + 4096 + wid * 1024);
      gload16(vsrc0 + kvn, vd + wid * 1024);
      gload16(vsrc1 + kvn, vd + 4096 + wid * 1024);
    }
    const int kv0 = it * 64;
    const char* kT = (char*)kTl + (it & 1) * 8192;
    const char* vT = (char*)vTl + (it & 1) * 8192;

    float sc[4][4];
    __builtin_amdgcn_s_setprio(1);
#pragma unroll
    for (int cf = 0; cf < 4; ++cf) {
      const int row = cf * 16 + ln;
      const int swz = row & 7;
      const bf16x8_t b0 = *(const bf16x8_t*)(kT + row * 128 + ((hi ^ swz) * 16));
      const bf16x8_t b1 = *(const bf16x8_t*)(kT + row * 128 + (((4 + hi) ^ swz) * 16));
      f32x4_t zacc = {};
      zacc = mfma16(aq0, b0, zacc);
      zacc = mfma16(aq1, b1, zacc);
#pragma unroll
      for (int r = 0; r < 4; ++r) sc[cf][r] = zacc[r] * 0.125f;
    }
    __builtin_amdgcn_s_setprio(0);
    if (kv0 + 63 > q0w) {
#pragma unroll
      for (int cf = 0; cf < 4; ++cf)
#pragma unroll
        for (int r = 0; r < 4; ++r) {
          const int qg = q0w + hi * 4 + r;
          const int kg = kv0 + cf * 16 + ln;
          if (kg > qg) sc[cf][r] = -1e30f;
        }
    }
#pragma unroll
    for (int r = 0; r < 4; ++r) {
      float tm = fmaxf(fmaxf(sc[0][r], sc[1][r]), fmaxf(sc[2][r], sc[3][r]));
      tm = fmaxf(tm, __shfl_xor(tm, 1));
      tm = fmaxf(tm, __shfl_xor(tm, 2));
      tm = fmaxf(tm, __shfl_xor(tm, 4));
      tm = fmaxf(tm, __shfl_xor(tm, 8));
      const float mn = fmaxf(m_r[r], tm);
      const float alpha = __expf(m_r[r] - mn);
      float rsum = 0.f;
#pragma unroll
      for (int cf = 0; cf < 4; ++cf) {
        const float p = __expf(sc[cf][r] - mn);
        sc[cf][r] = p; rsum += p;
      }
      rsum += __shfl_xor(rsum, 1); rsum += __shfl_xor(rsum, 2);
      rsum += __shfl_xor(rsum, 4); rsum += __shfl_xor(rsum, 8);
      l_r[r] = l_r[r] * alpha + rsum;
      m_r[r] = mn;
#pragma unroll
      for (int df = 0; df < 4; ++df) o_acc[df][r] *= alpha;
    }
    unsigned short* pw = &pl[wid][0];
#pragma unroll
    for (int cf = 0; cf < 4; ++cf)
#pragma unroll
      for (int r = 0; r < 4; ++r) {
        const int qq = hi * 4 + r;
        const int kv = cf * 16 + ln;
        const int bo = (qq * 128 + kv * 2) ^ ((qq & 7) << 4);
        *(unsigned short*)((char*)pw + bo) = f2bf(sc[cf][r]);
      }
    // P tile is wave-local: lgkmcnt drain suffices (no block barrier).
    asm volatile("s_waitcnt lgkmcnt(0)" ::: "memory");
    __builtin_amdgcn_sched_barrier(0);
    const bf16x8_t pa0 = *(const bf16x8_t*)((char*)pw + ((ln * 128 + hi * 16) ^ ((ln & 7) << 4)));
    const bf16x8_t pa1 = *(const bf16x8_t*)((char*)pw + ((ln * 128 + 64 + hi * 16) ^ ((ln & 7) << 4)));
    __builtin_amdgcn_s_setprio(1);
#pragma unroll
    for (int df = 0; df < 4; ++df) {
      const int d = df * 16 + ln;
      const int swz = d & 7;
      const bf16x8_t bv0 = *(const bf16x8_t*)(vT + d * 128 + ((hi ^ swz) * 16));
      const bf16x8_t bv1 = *(const bf16x8_t*)(vT + d * 128 + (((4 + hi) ^ swz) * 16));
      o_acc[df] = mfma16(pa0, bv0, o_acc[df]);
      o_acc[df] = mfma16(pa1, bv1, o_acc[df]);
    }
    __builtin_amdgcn_s_setprio(0);
    __syncthreads();  // drains prefetch (covered by compute) + buffer WAR protection
  }
#pragma unroll
  for (int df = 0; df < 4; ++df) {
    const int n = h * 64 + df * 16 + ln;
#pragma unroll
    for (int r = 0; r < 4; ++r) {
      const int m = q0w + hi * 4 + r;
      ao[(size_t)m * 1024 + n] = f2bf(o_acc[df][r] / l_r[r]);
    }
  }
}

// ---------------- gating + LN2: writes h2 (bf16) AND top-2 routing ----------------
__global__ __launch_bounds__(256) void gate_kernel(const float* __restrict__ x2, const float* __restrict__ g,
                                                   const float* __restrict__ b, const float* __restrict__ wg,
                                                   unsigned short* __restrict__ h2o,
                                                   int2* __restrict__ te, float2* __restrict__ tw,
                                                   int* __restrict__ cnt) {
  const int tid = threadIdx.x, wid = tid >> 6, lane = tid & 63;
  const int t = blockIdx.x * 4 + wid;
  const float* row = x2 + (size_t)t * 1024;
  float vv[16];
#pragma unroll
  for (int i = 0; i < 4; ++i) *(float4*)&vv[i * 4] = *(const float4*)(row + lane * 16 + i * 4);
  float s = 0.f, s2 = 0.f;
#pragma unroll
  for (int j = 0; j < 16; ++j) { s += vv[j]; s2 += vv[j] * vv[j]; }
#pragma unroll
  for (int o = 1; o < 64; o <<= 1) { s += __shfl_xor(s, o); s2 += __shfl_xor(s2, o); }
  const float mu = s * 0.0009765625f;
  const float var = s2 * 0.0009765625f - mu * mu;
  const float rs = rsqrtf(var + 1e-5f);
  float acc[8] = {0.f, 0.f, 0.f, 0.f, 0.f, 0.f, 0.f, 0.f};
  bf16x8_t o0, o1;
#pragma unroll
  for (int j = 0; j < 16; ++j) {
    const int d = lane * 16 + j;
    const float xv = (vv[j] - mu) * rs * g[d] + b[d];
    if (j < 8) o0[j] = (short)f2bf(xv); else o1[j - 8] = (short)f2bf(xv);
    const float4 w0 = *(const float4*)(wg + d * 8);
    const float4 w1 = *(const float4*)(wg + d * 8 + 4);
    acc[0] += xv * w0.x; acc[1] += xv * w0.y; acc[2] += xv * w0.z; acc[3] += xv * w0.w;
    acc[4] += xv * w1.x; acc[5] += xv * w1.y; acc[6] += xv * w1.z; acc[7] += xv * w1.w;
  }
  *(bf16x8_t*)(h2o + (size_t)t * 1024 + lane * 16) = o0;
  *(bf16x8_t*)(h2o + (size_t)t * 1024 + lane * 16 + 8) = o1;
#pragma unroll
  for (int o = 1; o < 64; o <<= 1) {
#pragma unroll
    for (int e = 0; e < 8; ++e) acc[e] += __shfl_xor(acc[e], o);
  }
  if (lane == 0) {
    float sg[8];
#pragma unroll
    for (int e = 0; e < 8; ++e) sg[e] = 1.f / (1.f + __expf(-acc[e]));
    int e0 = 0;
#pragma unroll
    for (int e = 1; e < 8; ++e) if (sg[e] > sg[e0]) e0 = e;
    int e1 = (e0 == 0) ? 1 : 0;
#pragma unroll
    for (int e = 0; e < 8; ++e) if (e != e0 && sg[e] > sg[e1]) e1 = e;
    const float v0 = sg[e0], v1 = sg[e1];
    const float inv = 1.f / (v0 + v1 + 1e-9f);
    te[t] = make_int2(e0, e1);
    tw[t] = make_float2(v0 * inv, v1 * inv);
    atomicAdd(&cnt[e0], 1);
    atomicAdd(&cnt[e1], 1);
  }
}

__global__ void zero_counters(int* p) { if (threadIdx.x < 8) p[threadIdx.x] = 0; }

// ---------------- routing phase 2: 256-row tiles, padded offsets + metadata ----------------
__global__ __launch_bounds__(256) void g2_kernel(const int* __restrict__ cnt, int* __restrict__ slot_off,
                                                 int* __restrict__ tile_expert, int* __restrict__ tile_rowbase,
                                                 int* __restrict__ cursor, int* __restrict__ assign_token,
                                                 float* __restrict__ assign_w) {
  const int tid = threadIdx.x;
  for (int i = tid; i < 8192; i += 256) { assign_token[i] = -1; assign_w[i] = 0.f; }
  if (tid == 0) {
    int base = 0, tiles = 0;
    for (int e = 0; e < 8; ++e) {
      const int c = cnt[e];
      slot_off[e] = base;
      cursor[e] = 0;
      const int nt = (c + 255) >> 8;
      for (int i = 0; i < nt; ++i) {
        tile_expert[tiles] = e;
        tile_rowbase[tiles] = base + i * 256;
        ++tiles;
      }
      base += nt * 256;
    }
    for (; tiles < 40; ++tiles) tile_expert[tiles] = -1;
  }
}

// ---------------- routing phase 3: scatter assignments ----------------
__global__ __launch_bounds__(256) void g3_kernel(const int2* __restrict__ te, const float2* __restrict__ tw,
                                                 const int* __restrict__ slot_off, int* __restrict__ cursor,
                                                 int* __restrict__ assign_token, float* __restrict__ assign_w) {
  const int t = blockIdx.x * 256 + threadIdx.x;
  const int2 e = te[t];
  const float2 w = tw[t];
  const int s0 = slot_off[e.x] + atomicAdd(&cursor[e.x], 1);
  assign_token[s0] = t; assign_w[s0] = w.x;
  const int s1 = slot_off[e.y] + atomicAdd(&cursor[e.y], 1);
  assign_token[s1] = t; assign_w[s1] = w.y;
}

// ---- stage a 256x32 A tile (16KB) = 4 gload16 ----
DI void stageA4(const unsigned short* a0, const unsigned short* a1,
                const unsigned short* a2, const unsigned short* a3,
                int koff, char* Ab, int wid) {
  gload16(a0 + koff, Ab + wid * 1024);
  gload16(a1 + koff, Ab + 4096 + wid * 1024);
  gload16(a2 + koff, Ab + 8192 + wid * 1024);
  gload16(a3 + koff, Ab + 12288 + wid * 1024);
}
// ---- stage a 128x32 A tile (8KB) = 2 gload16 ----
DI void stageA2(const unsigned short* a0, const unsigned short* a1,
                int koff, char* Ab, int wid) {
  gload16(a0 + koff, Ab + wid * 1024);
  gload16(a1 + koff, Ab + 4096 + wid * 1024);
}

// ---- upgate helpers (BM=256) ----
DI void ug_write_b(char* Bn, const int* boff, const float4& q0, const float4& q1,
                   const float4& q2, const float4& q3) {
  const float* q0p = (const float*)&q0; const float* q1p = (const float*)&q1;
  const float* q2p = (const float*)&q2; const float* q3p = (const float*)&q3;
#pragma unroll
  for (int i = 0; i < 4; ++i) {
    uint2 w;
    w.x = pk2(q0p[i], q1p[i]);
    w.y = pk2(q2p[i], q3p[i]);
    *(uint2*)(Bn + boff[i]) = w;
  }
}

DI void ug_mfma256(const unsigned short* A, const char* Bb, int wr, int wc, int ln, int hi,
                   f32x4_t (&accg)[8][2], f32x4_t (&accu)[8][2]) {
  bf16x8_t af[8];
#pragma unroll
  for (int mf = 0; mf < 8; ++mf)
    af[mf] = frag(A, wr * 128 + mf * 16 + ln, hi);
  __builtin_amdgcn_s_setprio(1);
#pragma unroll
  for (int nf = 0; nf < 2; ++nf) {
    const int nrow = wc * 32 + nf * 16 + ln;
    int bo = nrow * 64 + hi * 16;
    bo ^= ((nrow >> 2) & 7) << 4;
    const bf16x8_t bg = *(const bf16x8_t*)(Bb + bo);
    const bf16x8_t bu = *(const bf16x8_t*)(Bb + 4096 + bo);
#pragma unroll
    for (int mf = 0; mf < 8; ++mf) {
      accg[mf][nf] = mfma16(af[mf], bg, accg[mf][nf]);
      accu[mf][nf] = mfma16(af[mf], bu, accu[mf][nf]);
    }
  }
  __builtin_amdgcn_s_setprio(0);
}

// ---------------- MoE up+gate: BM=256, A-first issue order (race-free 2-deep B) ----------
__global__ __launch_bounds__(256, 2) void upgate_kernel(const unsigned short* __restrict__ h2,
                                                        const float* __restrict__ w_eg, const float* __restrict__ w_eu,
                                                        const int* __restrict__ tile_expert,
                                                        const int* __restrict__ tile_rowbase,
                                                        const int* __restrict__ assign_token,
                                                        unsigned short* __restrict__ act) {
  const int by = blockIdx.y;
  const int e = tile_expert[by];
  if (e < 0) return;
  const int n0 = blockIdx.x * 64;
  const int rowbase = tile_rowbase[by];
  const int tid = threadIdx.x;
  __shared__ unsigned short lds[2 * 8192 + 2 * 4096];  // A dbuf 2x16KB, B dbuf 2x8KB
  char* A0 = (char*)lds;
  char* A1 = (char*)lds + 16384;
  char* B0 = (char*)lds + 32768;
  char* B1 = (char*)lds + 40960;
  const int wid = tid >> 6, lane = tid & 63, ln = lane & 15, hi = lane >> 4;
  const int wr = wid >> 1, wc = wid & 1;
  const int r0s = rowbase + (tid >> 2);
  int tk0 = assign_token[r0s];        tk0 = tk0 < 0 ? 0 : tk0;
  int tk1 = assign_token[r0s + 64];   tk1 = tk1 < 0 ? 0 : tk1;
  int tk2 = assign_token[r0s + 128];  tk2 = tk2 < 0 ? 0 : tk2;
  int tk3 = assign_token[r0s + 192];  tk3 = tk3 < 0 ? 0 : tk3;
  const int cs = chunk_swz(tid);
  const unsigned short* aR0 = h2 + (size_t)tk0 * 1024 + cs;
  const unsigned short* aR1 = h2 + (size_t)tk1 * 1024 + cs;
  const unsigned short* aR2 = h2 + (size_t)tk2 * 1024 + cs;
  const unsigned short* aR3 = h2 + (size_t)tk3 * 1024 + cs;
  const int mat = tid >> 7;
  const int blk = tid & 127;
  const int kb = (blk >> 4) * 4;
  const int nb = (blk & 15) * 4;
  const float* bsrc = (mat ? w_eu : w_eg) + (size_t)e * 1024 * 4096 + (size_t)kb * 4096 + n0 + nb;
  int boff[4];
#pragma unroll
  for (int i = 0; i < 4; ++i) {
    const int n = nb + i;
    int bo = mat * 4096 + n * 64 + kb * 2;
    bo ^= ((n >> 2) & 7) << 4;
    boff[i] = bo;
  }
  f32x4_t accg[8][2] = {};
  f32x4_t accu[8][2] = {};
  float4 qA0, qA1, qA2, qA3, qB0, qB1, qB2, qB3;
  // ---- prologue: A(0)->A0; B(0)->regs; write B0 (drains A(0) too, FIFO); B(1)->qA ----
  stageA4(aR0, aR1, aR2, aR3, 0, A0, wid);
  qB0 = *(const float4*)(bsrc);
  qB1 = *(const float4*)(bsrc + 4096);
  qB2 = *(const float4*)(bsrc + 8192);
  qB3 = *(const float4*)(bsrc + 12288);
  __builtin_amdgcn_sched_barrier(0);
  ug_write_b(B0, boff, qB0, qB1, qB2, qB3);
  {
    const float* bs = bsrc + (size_t)32 * 4096;
    qA0 = *(const float4*)(bs);
    qA1 = *(const float4*)(bs + 4096);
    qA2 = *(const float4*)(bs + 8192);
    qA3 = *(const float4*)(bs + 12288);
  }
  asm volatile("s_waitcnt lgkmcnt(0)" ::: "memory");
  __builtin_amdgcn_sched_barrier(0);
  __builtin_amdgcn_s_barrier();
  // ---- main: t = 0..29 (15 pairs) ----
  for (int p = 0; p < 15; ++p) {
    {  // even t=2p: compute A0/B0; stage A(t+1)->A1; load B(t+2)->qB
      const int t = 2 * p;
      stageA4(aR0, aR1, aR2, aR3, (t + 1) * 32, A1, wid);
      const float* bs = bsrc + (size_t)(t + 2) * 32 * 4096;
      qB0 = *(const float4*)(bs);
      qB1 = *(const float4*)(bs + 4096);
      qB2 = *(const float4*)(bs + 8192);
      qB3 = *(const float4*)(bs + 12288);
      __builtin_amdgcn_sched_barrier(0);
      ug_write_b(B1, boff, qA0, qA1, qA2, qA3);   // implied vmcnt(8): keeps A(t+1)+B(t+2)
      ug_mfma256((const unsigned short*)A0, B0, wr, wc, ln, hi, accg, accu);
      asm volatile("s_waitcnt vmcnt(4)" ::: "memory");  // retire A(t+1)x4; keep B(t+2)x4
      __builtin_amdgcn_sched_barrier(0);
      asm volatile("s_waitcnt lgkmcnt(0)" ::: "memory");
      __builtin_amdgcn_sched_barrier(0);
      __builtin_amdgcn_s_barrier();
    }
    {  // odd t=2p+1: compute A1/B1
      const int t = 2 * p + 1;
      stageA4(aR0, aR1, aR2, aR3, (t + 1) * 32, A0, wid);
      const float* bs = bsrc + (size_t)(t + 2) * 32 * 4096;
      qA0 = *(const float4*)(bs);
      qA1 = *(const float4*)(bs + 4096);
      qA2 = *(const float4*)(bs + 8192);
      qA3 = *(const float4*)(bs + 12288);
      __builtin_amdgcn_sched_barrier(0);
      ug_write_b(B0, boff, qB0, qB1, qB2, qB3);
      ug_mfma256((const unsigned short*)A1, B1, wr, wc, ln, hi, accg, accu);
      asm volatile("s_waitcnt vmcnt(4)" ::: "memory");
      __builtin_amdgcn_sched_barrier(0);
      asm volatile("s_waitcnt lgkmcnt(0)" ::: "memory");
      __builtin_amdgcn_sched_barrier(0);
      __builtin_amdgcn_s_barrier();
    }
  }
  // ---- t=30 (A0/B0): stage A(31)->A1; write B(31) from qA; drain all ----
  stageA4(aR0, aR1, aR2, aR3, 31 * 32, A1, wid);
  __builtin_amdgcn_sched_barrier(0);
  ug_write_b(B1, boff, qA0, qA1, qA2, qA3);   // implied vmcnt(4): keeps A(31)
  ug_mfma256((const unsigned short*)A0, B0, wr, wc, ln, hi, accg, accu);
  asm volatile("s_waitcnt vmcnt(0)" ::: "memory");
  __builtin_amdgcn_sched_barrier(0);
  asm volatile("s_waitcnt lgkmcnt(0)" ::: "memory");
  __builtin_amdgcn_sched_barrier(0);
  __builtin_amdgcn_s_barrier();
  // ---- t=31: MFMA only ----
  ug_mfma256((const unsigned short*)A1, B1, wr, wc, ln, hi, accg, accu);
#pragma unroll
  for (int mf = 0; mf < 8; ++mf)
#pragma unroll
    for (int nf = 0; nf < 2; ++nf)
#pragma unroll
      for (int r = 0; r < 4; ++r) {
        const int m = wr * 128 + mf * 16 + hi * 4 + r;
        const int n = n0 + wc * 32 + nf * 16 + ln;
        const float gv = accg[mf][nf][r], uv = accu[mf][nf][r];
        const float val = gv / (1.f + __expf(-gv)) * uv;
        act[(size_t)(rowbase + m) * 4096 + n] = f2bf(val);
      }
}

// ---- down helpers (BM=128) ----
DI void dn_write_b(char* Bn, const int* boff, const float4& q0, const float4& q1) {
  const float* q0p = (const float*)&q0; const float* q1p = (const float*)&q1;
#pragma unroll
  for (int i = 0; i < 4; ++i)
    *(uint32_t*)(Bn + boff[i]) = pk2(q0p[i], q1p[i]);
}

DI void dn_mfma(const unsigned short* A, const char* Bb, int wr, int wc, int ln, int hi,
                f32x4_t (&acc)[4][2]) {
  bf16x8_t af[4];
#pragma unroll
  for (int mf = 0; mf < 4; ++mf)
    af[mf] = frag(A, wr * 64 + mf * 16 + ln, hi);
  __builtin_amdgcn_s_setprio(1);
#pragma unroll
  for (int nf = 0; nf < 2; ++nf) {
    const int nrow = wc * 32 + nf * 16 + ln;
    int bo = nrow * 64 + hi * 16;
    bo ^= ((nrow >> 2) & 7) << 4;
    const bf16x8_t bb = *(const bf16x8_t*)(Bb + bo);
#pragma unroll
    for (int mf = 0; mf < 4; ++mf)
      acc[mf][nf] = mfma16(af[mf], bb, acc[mf][nf]);
  }
  __builtin_amdgcn_s_setprio(0);
}

// ---------------- MoE down: BM=128, split-K x4 (free via atomicAdd), A-first order --------
__global__ __launch_bounds__(256) void down_kernel(const unsigned short* __restrict__ act,
                                                   const float* __restrict__ w_ed,
                                                   const int* __restrict__ tile_expert,
                                                   const int* __restrict__ tile_rowbase,
                                                   const int* __restrict__ assign_token,
                                                   const float* __restrict__ assign_w,
                                                   float* __restrict__ out) {
  const int tix = blockIdx.y;
  const int e = tile_expert[tix >> 1];
  if (e < 0) return;
  const int rowbase = tile_rowbase[tix >> 1] + (tix & 1) * 128;
  const int n0 = blockIdx.x * 64;
  const int kz = blockIdx.z * 1024;
  const int tid = threadIdx.x;
  __shared__ unsigned short lds[2 * 4096 + 2 * 2048];  // A dbuf 2x8KB, B dbuf 2x4KB
  char* A0 = (char*)lds;
  char* A1 = (char*)lds + 8192;
  char* B0 = (char*)lds + 16384;
  char* B1 = (char*)lds + 20480;
  const int wid = tid >> 6, lane = tid & 63, ln = lane & 15, hi = lane >> 4;
  const int wr = wid >> 1, wc = wid & 1;
  const int cs = chunk_swz(tid);
  const unsigned short* aR0 = act + (size_t)(rowbase + (tid >> 2)) * 4096 + kz + cs;
  const unsigned short* aR1 = aR0 + (size_t)64 * 4096;
  const int nb = (tid & 15) * 4;
  const int kb2 = (tid >> 4) * 2;
  const float* bsrc = w_ed + (size_t)e * 4096 * 1024 + (size_t)(kz + kb2) * 1024 + n0 + nb;
  int boff[4];
#pragma unroll
  for (int i = 0; i < 4; ++i) {
    const int n = nb + i;
    int bo = n * 64 + kb2 * 2;
    bo ^= ((n >> 2) & 7) << 4;
    boff[i] = bo;
  }
  f32x4_t acc[4][2] = {};
  float4 qA0, qA1, qB0, qB1;
  // ---- prologue ----
  stageA2(aR0, aR1, 0, A0, wid);
  qB0 = *(const float4*)(bsrc);
  qB1 = *(const float4*)(bsrc + 1024);
  __builtin_amdgcn_sched_barrier(0);
  dn_write_b(B0, boff, qB0, qB1);   // implied wait drains A(0) too (older in FIFO)
  {
    const float* bs = bsrc + (size_t)32 * 1024;
    qA0 = *(const float4*)(bs);
    qA1 = *(const float4*)(bs + 1024);
  }
  asm volatile("s_waitcnt lgkmcnt(0)" ::: "memory");
  __builtin_amdgcn_sched_barrier(0);
  __builtin_amdgcn_s_barrier();
  // ---- main: t = 0..29 (15 pairs) ----
  for (int p = 0; p < 15; ++p) {
    {  // even t=2p
      const int t = 2 * p;
      stageA2(aR0, aR1, (t + 1) * 32, A1, wid);
      const float* bs = bsrc + (size_t)(t + 2) * 32 * 1024;
      qB0 = *(const float4*)(bs);
      qB1 = *(const float4*)(bs + 1024);
      __builtin_amdgcn_sched_barrier(0);
      dn_write_b(B1, boff, qA0, qA1);   // implied vmcnt(4): keeps A(t+1)x2 + B(t+2)x2
      dn_mfma((const unsigned short*)A0, B0, wr, wc, ln, hi, acc);
      asm volatile("s_waitcnt vmcnt(2)" ::: "memory");  // retire A(t+1); keep B(t+2)
      __builtin_amdgcn_sched_barrier(0);
      asm volatile("s_waitcnt lgkmcnt(0)" ::: "memory");
      __builtin_amdgcn_sched_barrier(0);
      __builtin_amdgcn_s_barrier();
    }
    {  // odd t=2p+1
      const int t = 2 * p + 1;
      stageA2(aR0, aR1, (t + 1) * 32, A0, wid);
      const float* bs = bsrc + (size_t)(t + 2) * 32 * 1024;
      qA0 = *(const float4*)(bs);
      qA1 = *(const float4*)(bs + 1024);
      __builtin_amdgcn_sched_barrier(0);
      dn_write_b(B0, boff, qB0, qB1);
      dn_mfma((const unsigned short*)A1, B1, wr, wc, ln, hi, acc);
      asm volatile("s_waitcnt vmcnt(2)" ::: "memory");
      __builtin_amdgcn_sched_barrier(0);
      asm volatile("s_waitcnt lgkmcnt(0)" ::: "memory");
      __builtin_amdgcn_sched_barrier(0);
      __builtin_amdgcn_s_barrier();
    }
  }
  // ---- t=30: stage A(31); write B(31) from qA; drain ----
  stageA2(aR0, aR1, 31 * 32, A1, wid);
  __builtin_amdgcn_sched_barrier(0);
  dn_write_b(B1, boff, qA0, qA1);
  dn_mfma((const unsigned short*)A0, B0, wr, wc, ln, hi, acc);
  asm volatile("s_waitcnt vmcnt(0)" ::: "memory");
  __builtin_amdgcn_sched_barrier(0);
  asm volatile("s_waitcnt lgkmcnt(0)" ::: "memory");
  __builtin_amdgcn_sched_barrier(0);
  __builtin_amdgcn_s_barrier();
  // ---- t=31 ----
  dn_mfma((const unsigned short*)A1, B1, wr, wc, ln, hi, acc);
#pragma unroll
  for (int mf = 0; mf < 4; ++mf)
#pragma unroll
    for (int r = 0; r < 4; ++r) {
      const int m = wr * 64 + mf * 16 + hi * 4 + r;
      const int slot = rowbase + m;
      const int tk = assign_token[slot];
      if (tk >= 0) {
        const float w = assign_w[slot];
#pragma unroll
        for (int nf = 0; nf < 2; ++nf) {
          const int n = n0 + wc * 32 + nf * 16 + ln;
          atomicAdd(out + (size_t)tk * 1024 + n, acc[mf][nf][r] * w);
        }
      }
    }
}

// ---------------- host launcher ----------------
extern "C" void kernel_launch(void* const* d_in, const int* in_sizes, int n_in,
                              void* d_out, int out_size, void* d_ws, size_t ws_size,
                              hipStream_t stream) {
  (void)in_sizes; (void)n_in; (void)out_size;
  const float* x    = (const float*)d_in[0];
  const float* ln1g = (const float*)d_in[1];
  const float* ln1b = (const float*)d_in[2];
  const float* wq   = (const float*)d_in[3];
  const float* wk   = (const float*)d_in[4];
  const float* wv   = (const float*)d_in[5];
  const float* wo   = (const float*)d_in[6];
  const float* ln2g = (const float*)d_in[7];
  const float* ln2b = (const float*)d_in[8];
  const float* wg   = (const float*)d_in[9];
  const float* weg  = (const float*)d_in[10];
  const float* weu  = (const float*)d_in[11];
  const float* wed  = (const float*)d_in[12];
  float* out = (float*)d_out;
  char* ws = (char*)d_ws;

  const size_t MB = (size_t)1 << 20;
  if (ws_size < 86 * MB) return;
  unsigned short* wqT = (unsigned short*)(ws + 0 * MB);
  unsigned short* wkT = (unsigned short*)(ws + 2 * MB);
  unsigned short* wvT = (unsigned short*)(ws + 4 * MB);
  unsigned short* woT = (unsigned short*)(ws + 6 * MB);
  unsigned short* h1  = (unsigned short*)(ws + 8 * MB);
  unsigned short* qb  = (unsigned short*)(ws + 12 * MB);
  unsigned short* kbf = (unsigned short*)(ws + 16 * MB);
  unsigned short* vt  = (unsigned short*)(ws + 20 * MB);
  unsigned short* ao  = (unsigned short*)(ws + 24 * MB);
  unsigned short* h2  = (unsigned short*)(ws + 28 * MB);
  unsigned short* act = (unsigned short*)(ws + 32 * MB);  // 6144*4096*2 = 48MiB (52MB slot)
  int2*   te = (int2*)(ws + 84 * MB);
  float2* tw = (float2*)(ws + 84 * MB + 16384);
  int*  meta = (int*)(ws + 84 * MB + 32768);
  int* cnt = meta;
  int* cursor = meta + 8;
  int* slot_off = meta + 16;
  int* tile_expert = meta + 24;
  int* tile_rowbase = meta + 64;
  int*   assign_token = (int*)(ws + 84 * MB + 36864);
  float* assign_w     = (float*)(ws + 84 * MB + 36864 + 32768);

  zero_counters<<<1, 64, 0, stream>>>(cnt);
  transpose_cvt4<<<dim3(16, 16, 4), 256, 0, stream>>>(wq, wk, wv, wo, wqT, wkT, wvT, woT);
  ln_kernel<<<2048, 256, 0, stream>>>(x, ln1g, ln1b, h1);
  qkv_kernel<<<dim3(8, 16, 3), 256, 0, stream>>>(h1, wqT, wkT, wvT, qb, kbf, vt);
  attn_kernel<<<dim3(32, 16), 256, 0, stream>>>(qb, kbf, vt, ao);
  wo_kernel<<<dim3(16, 16), 256, 0, stream>>>(ao, woT, x, out);
  gate_kernel<<<512, 256, 0, stream>>>(out, ln2g, ln2b, wg, h2, te, tw, cnt);
  g2_kernel<<<1, 256, 0, stream>>>(cnt, slot_off, tile_expert, tile_rowbase, cursor, assign_token, assign_w);
  g3_kernel<<<8, 256, 0, stream>>>(te, tw, slot_off, cursor, assign_token, assign_w);
  upgate_kernel<<<dim3(64, 24), 256, 0, stream>>>(h2, weg, weu, tile_expert, tile_rowbase, assign_token, act);
  down_kernel<<<dim3(16, 48, 4), 256, 0, stream>>>(act, wed, tile_expert, tile_rowbase, assign_token, assign_w, out);
}